// Round 6
// baseline (2388.733 us; speedup 1.0000x reference)
//
#include <hip/hip_runtime.h>
#include <hip/hip_bf16.h>

namespace {

constexpr int C = 128, N = 256, T = 64, Bsz = 8;
constexpr int TILE = T * C;                       // 8192 elements per (b,n) slab
constexpr size_t BIGE = (size_t)Bsz * N * T * C;  // 16,777,216 elements

__device__ __forceinline__ float bfu(unsigned short u) {
  unsigned int x = ((unsigned int)u) << 16;
  return __uint_as_float(x);
}
// flag-aware load: f32 != 0 -> input is fp32, else bf16
__device__ __forceinline__ float ld(const void* p, size_t i, int f32) {
  if (f32) return ((const float*)p)[i];
  return bfu(((const unsigned short*)p)[i]);
}
__device__ __forceinline__ float sigm(float x) { return 1.f / (1.f + __expf(-x)); }

// ---------------------------------------------------------------- dtype sniffer
__global__ __launch_bounds__(64) void k_sniff(const unsigned short* x, int* flag) {
  __shared__ int cnt[64];
  int tid = threadIdx.x;
  int c = 0;
  for (int u = 0; u < 8; ++u) {
    unsigned short v = x[tid * 8 + u];
    int e = (v >> 7) & 255;
    c += (e >= 97 && e <= 157) ? 1 : 0;
  }
  cnt[tid] = c;
  __syncthreads();
  if (tid == 0) {
    int s = 0;
    for (int i = 0; i < 64; ++i) s += cnt[i];
    flag[0] = (s < 435) ? 1 : 0;  // <85% plausible-bf16 words -> fp32 input
  }
}

// ---------------------------------------------------------------- x -> fp32 copy
__global__ __launch_bounds__(256) void k_cvtx(const void* x, const int* flag, float* xf) {
  int f = flag[0];
  size_t i0 = ((size_t)blockIdx.x * 256 + threadIdx.x) * 4;
  size_t stride = (size_t)gridDim.x * 1024;
  if (f) {
    const float4* src = (const float4*)x;
    for (size_t i = i0; i < BIGE; i += stride) *(float4*)&xf[i] = src[i >> 2];
  } else {
    const ushort4* src = (const ushort4*)x;
    for (size_t i = i0; i < BIGE; i += stride) {
      ushort4 u = src[i >> 2];
      float4 v; v.x = bfu(u.x); v.y = bfu(u.y); v.z = bfu(u.z); v.w = bfu(u.w);
      *(float4*)&xf[i] = v;
    }
  }
}

// ---------------------------------------------------------------- prep (weights -> fp32, k-major)
struct PrepArgs {
  const int* flag;
  const void *wq, *wk, *w1, *w2, *th, *dxc, *dec, *dc1;
  const void *bq, *bk, *b1, *b2, *l0g, *l0b, *l1g, *l1b, *dxcb, *decb, *dc1b, *dp2w, *dp2b;
  float *wqkT, *w1T, *w2T, *thT, *dxcT, *decT, *dc1T;
  float *bqk, *b1f, *b2f, *l0gf, *l0bf, *l1gf, *l1bf, *dxcbf, *decbf, *dc1bf, *dp2wf, *dp2bf;
};

__global__ __launch_bounds__(256) void k_prep(PrepArgs a) {
  int f = a.flag[0];
  int idx = blockIdx.x * blockDim.x + threadIdx.x;
  int stride = gridDim.x * blockDim.x;
  for (int i = idx; i < 384 * 256; i += stride) {
    int k = i >> 8, o = i & 255, j = k >> 7, ii = k & 127;
    a.wqkT[i] = (o < 128) ? ld(a.wq, (o * 128 + ii) * 3 + j, f)
                          : ld(a.wk, ((o - 128) * 128 + ii) * 3 + j, f);
  }
  for (int i = idx; i < 16384; i += stride) {
    int k = i >> 7, o = i & 127;
    a.w1T[i] = ld(a.w1, o * 128 + k, f);
    a.w2T[i] = ld(a.w2, o * 128 + k, f);
    a.thT[i] = ld(a.th, o * 128 + k, f);
  }
  for (int i = idx; i < 384 * 128; i += stride) {
    int k = i >> 7, o = i & 127, j = k >> 7, ii = k & 127;
    int s = (o * 128 + ii) * 3 + j;
    a.dxcT[i] = ld(a.dxc, s, f); a.decT[i] = ld(a.dec, s, f); a.dc1T[i] = ld(a.dc1, s, f);
  }
  for (int i = idx; i < 256; i += stride) {
    a.bqk[i] = (i < 128) ? ld(a.bq, i, f) : ld(a.bk, i - 128, f);
    a.dp2wf[i] = ld(a.dp2w, i, f);
  }
  for (int i = idx; i < 128; i += stride) {
    a.b1f[i] = ld(a.b1, i, f);   a.b2f[i] = ld(a.b2, i, f);
    a.l0gf[i] = ld(a.l0g, i, f); a.l0bf[i] = ld(a.l0b, i, f);
    a.l1gf[i] = ld(a.l1g, i, f); a.l1bf[i] = ld(a.l1b, i, f);
    a.dxcbf[i] = ld(a.dxcb, i, f); a.decbf[i] = ld(a.decb, i, f); a.dc1bf[i] = ld(a.dc1b, i, f);
  }
  if (idx < 2) a.dp2bf[idx] = ld(a.dp2b, idx, f);
}

__global__ __launch_bounds__(256) void k_lap(const void* adj, const int* flag, float* lap) {
  __shared__ float dsh[256];
  int f = flag[0];
  int tid = threadIdx.x;
  float s = 0.f;
  for (int m = 0; m < 256; ++m) s += ld(adj, tid * 256 + m, f);
  dsh[tid] = 1.f / sqrtf(s);
  __syncthreads();
  for (int idx = tid; idx < 65536; idx += 256) {
    int n = idx >> 8, m = idx & 255;
    lap[idx] = ld(adj, idx, f) * dsh[n] * dsh[m];
  }
}

__global__ __launch_bounds__(128) void k_emb(const int* step, const int* flag,
                                             const void* p1w, const void* p1b,
                                             const void* p2w, const void* p2b, float* e) {
  int b = blockIdx.x, c = threadIdx.x;
  int f = flag[0];
  __shared__ float tab[128], e1[128];
  float sv = (float)step[b];
  int i0 = c & 63;
  float fr = powf(10.f, (float)i0 / 63.f * 4.f);
  float ang = sv * fr;
  tab[c] = (c < 64) ? sinf(ang) : cosf(ang);
  __syncthreads();
  float a = ld(p1b, c, f);
  for (int i = 0; i < 128; ++i) a += tab[i] * ld(p1w, c * 128 + i, f);
  a = a * sigm(a);
  e1[c] = a;
  __syncthreads();
  float a2 = ld(p2b, c, f);
  for (int i = 0; i < 128; ++i) a2 += e1[i] * ld(p2w, c * 128 + i, f);
  e[b * 128 + c] = a2 * sigm(a2);
}

// ================================================================ mega1 v4 (1024 threads):
// per (b,n): x -> QK conv GEMM, V GEMM, 8-head temporal attention (register
// softmax, width-16 shuffles), o.w2^T, LN0 + residual -> xp (fp32) to g0.
__global__ __launch_bounds__(1024, 1) void k_mega1(
    const float* xf, const float* wqkT, const float* bqk,
    const float* w1T, const float* b1f, const float* w2T, const float* b2f,
    const float* l0g, const float* l0b, float* g0) {
  int bn = blockIdx.x, b = bn >> 8, n = bn & 255;
  __shared__ float xs[128 * 68];    // x tile, [c][t+1], zero pads at tt=0,65
  __shared__ float qls[64 * 132];   // q [t][c]; later o [t][c]
  __shared__ float kls[64 * 132];   // k [t][c]; later o.w2^T [t][c]
  __shared__ float vls[64 * 132];   // v [t][c]; later o^T [c*66+t]
  __shared__ float mrow[64], vrow[64];
  int tid = threadIdx.x;
  const float* xb = xf + (size_t)b * C * N * T + (size_t)n * T;
  for (int idx = tid * 4; idx < TILE; idx += 4096) {
    int i = idx >> 6, t = idx & 63;
    float4 v4 = *(const float4*)&xb[(size_t)i * N * T + t];
    float* row = &xs[i * 68 + t + 1];
    row[0] = v4.x; row[1] = v4.y; row[2] = v4.z; row[3] = v4.w;
  }
  if (tid < 128) { xs[tid * 68] = 0.f; xs[tid * 68 + 65] = 0.f; }
  __syncthreads();
  // ---- QK conv GEMM (K=384, 256 cols) -> qls, kls.  4 t x 4 o per thread.
  {
    int cg = tid & 63, tc = tid >> 6;      // tc 0..15
    int o0 = cg * 4, t0 = tc * 4;
    float4 bi = *(const float4*)&bqk[o0];
    float acc[4][4];
#pragma unroll
    for (int t = 0; t < 4; ++t) { acc[t][0] = bi.x; acc[t][1] = bi.y; acc[t][2] = bi.z; acc[t][3] = bi.w; }
    for (int i = 0; i < 128; ++i) {
      const float* xr = &xs[i * 68 + t0];
      float xv[6];
#pragma unroll
      for (int u = 0; u < 6; ++u) xv[u] = xr[u];
#pragma unroll
      for (int j = 0; j < 3; ++j) {
        float4 w4 = *(const float4*)&wqkT[(j * 128 + i) * 256 + o0];
#pragma unroll
        for (int t = 0; t < 4; ++t) {
          float xvv = xv[t + j];
          acc[t][0] += xvv * w4.x; acc[t][1] += xvv * w4.y;
          acc[t][2] += xvv * w4.z; acc[t][3] += xvv * w4.w;
        }
      }
    }
    float* dst = (o0 < 128) ? qls : kls;
    int oo = o0 & 127;
#pragma unroll
    for (int t = 0; t < 4; ++t) {
      float4 r4; r4.x = acc[t][0]; r4.y = acc[t][1]; r4.z = acc[t][2]; r4.w = acc[t][3];
      *(float4*)&dst[(t0 + t) * 132 + oo] = r4;
    }
  }
  // ---- V GEMM (K=128) -> vls.  2 t x 4 o per thread.
  {
    int cg = tid & 31, tc = tid >> 5;      // tc 0..31
    int o0 = cg * 4, t0 = tc * 2;
    float4 bi = *(const float4*)&b1f[o0];
    float acc[2][4];
#pragma unroll
    for (int t = 0; t < 2; ++t) { acc[t][0] = bi.x; acc[t][1] = bi.y; acc[t][2] = bi.z; acc[t][3] = bi.w; }
    for (int i = 0; i < 128; ++i) {
      const float* xr = &xs[i * 68 + t0 + 1];
      float x0 = xr[0], x1 = xr[1];
      float4 w4 = *(const float4*)&w1T[i * 128 + o0];
      acc[0][0] += x0 * w4.x; acc[0][1] += x0 * w4.y; acc[0][2] += x0 * w4.z; acc[0][3] += x0 * w4.w;
      acc[1][0] += x1 * w4.x; acc[1][1] += x1 * w4.y; acc[1][2] += x1 * w4.z; acc[1][3] += x1 * w4.w;
    }
#pragma unroll
    for (int t = 0; t < 2; ++t) {
      float4 r4; r4.x = acc[t][0]; r4.y = acc[t][1]; r4.z = acc[t][2]; r4.w = acc[t][3];
      *(float4*)&vls[(t0 + t) * 132 + o0] = r4;
    }
  }
  __syncthreads();
  // ---- temporal attention: 16-lane group per q-row t; heads sequential.
  {
    int t = tid >> 4;      // 0..63 (q row)
    int sg = tid & 15;     // lane in row-group
    for (int h = 0; h < 8; ++h) {
      int hb = h * 16;
      float4 q0 = *(const float4*)&qls[t * 132 + hb];
      float4 q1 = *(const float4*)&qls[t * 132 + hb + 4];
      float4 q2 = *(const float4*)&qls[t * 132 + hb + 8];
      float4 q3 = *(const float4*)&qls[t * 132 + hb + 12];
      float a[4];
#pragma unroll
      for (int j = 0; j < 4; ++j) {
        int s = sg + 16 * j;
        const float* kr = &kls[s * 132 + hb];
        float4 k0 = *(const float4*)&kr[0];
        float4 k1 = *(const float4*)&kr[4];
        float4 k2 = *(const float4*)&kr[8];
        float4 k3 = *(const float4*)&kr[12];
        a[j] = (q0.x * k0.x + q0.y * k0.y + q0.z * k0.z + q0.w * k0.w +
                q1.x * k1.x + q1.y * k1.y + q1.z * k1.z + q1.w * k1.w +
                q2.x * k2.x + q2.y * k2.y + q2.z * k2.z + q2.w * k2.w +
                q3.x * k3.x + q3.y * k3.y + q3.z * k3.z + q3.w * k3.w) * 0.25f;
      }
      float mx = fmaxf(fmaxf(a[0], a[1]), fmaxf(a[2], a[3]));
#pragma unroll
      for (int m = 8; m > 0; m >>= 1) mx = fmaxf(mx, __shfl_xor(mx, m, 16));
      float sum = 0.f;
#pragma unroll
      for (int j = 0; j < 4; ++j) { a[j] = __expf(a[j] - mx); sum += a[j]; }
#pragma unroll
      for (int m = 8; m > 0; m >>= 1) sum += __shfl_xor(sum, m, 16);
      float inv = 1.f / sum;
#pragma unroll
      for (int j = 0; j < 4; ++j) a[j] *= inv;
      float o[16];
#pragma unroll
      for (int d = 0; d < 16; ++d) o[d] = 0.f;
#pragma unroll
      for (int j = 0; j < 4; ++j) {
        int s = sg + 16 * j;
        const float* vr = &vls[s * 132 + hb];
        float w = a[j];
#pragma unroll
        for (int d = 0; d < 16; ++d) o[d] += w * vr[d];
      }
#pragma unroll
      for (int m = 8; m > 0; m >>= 1)
#pragma unroll
        for (int d = 0; d < 16; ++d) o[d] += __shfl_xor(o[d], m, 16);
      if (sg < 4) {
        float4 r4;
        r4.x = o[sg * 4 + 0]; r4.y = o[sg * 4 + 1];
        r4.z = o[sg * 4 + 2]; r4.w = o[sg * 4 + 3];
        *(float4*)&qls[t * 132 + hb + sg * 4] = r4;
      }
    }
  }
  __syncthreads();
  // ---- transpose o -> tr (reuse vls as [c*66 + t])
  float* tr = vls;
  for (int idx = tid; idx < TILE; idx += 1024) {
    int t = idx >> 7, c = idx & 127;
    tr[c * 66 + t] = qls[t * 132 + c];
  }
  __syncthreads();
  // ---- w2 GEMM: ls[t][o] = sum_i o[t][i]*w2[o][i] + b2 -> kls. 2 t x 4 o.
  {
    int cg = tid & 31, tc = tid >> 5;
    int o0 = cg * 4, t0 = tc * 2;
    float4 bi = *(const float4*)&b2f[o0];
    float acc[2][4];
#pragma unroll
    for (int t = 0; t < 2; ++t) { acc[t][0] = bi.x; acc[t][1] = bi.y; acc[t][2] = bi.z; acc[t][3] = bi.w; }
    for (int i = 0; i < 128; ++i) {
      const float* xr = &tr[i * 66 + t0];
      float x0 = xr[0], x1 = xr[1];
      float4 w4 = *(const float4*)&w2T[i * 128 + o0];
      acc[0][0] += x0 * w4.x; acc[0][1] += x0 * w4.y; acc[0][2] += x0 * w4.z; acc[0][3] += x0 * w4.w;
      acc[1][0] += x1 * w4.x; acc[1][1] += x1 * w4.y; acc[1][2] += x1 * w4.z; acc[1][3] += x1 * w4.w;
    }
#pragma unroll
    for (int t = 0; t < 2; ++t) {
      float4 r4; r4.x = acc[t][0]; r4.y = acc[t][1]; r4.z = acc[t][2]; r4.w = acc[t][3];
      *(float4*)&kls[(t0 + t) * 132 + o0] = r4;
    }
  }
  __syncthreads();
  // ---- LN0 stats via shuffles: 16-lane group per row
  {
    int r = tid >> 4, sg = tid & 15;
    float s = 0.f, q2 = 0.f;
    const float* row = &kls[r * 132 + sg * 8];
    for (int u = 0; u < 8; ++u) {
      float v = row[u];
      s += v; q2 += v * v;
    }
#pragma unroll
    for (int m = 8; m > 0; m >>= 1) {
      s += __shfl_xor(s, m, 16);
      q2 += __shfl_xor(q2, m, 16);
    }
    if (sg == 0) {
      float mm = s * (1.f / 128.f);
      mrow[r] = mm;
      vrow[r] = rsqrtf(q2 * (1.f / 128.f) - mm * mm + 1e-5f);
    }
  }
  __syncthreads();
  float* dst = g0 + (size_t)bn * TILE;
  for (int idx = tid; idx < TILE; idx += 1024) {
    int t = idx >> 7, c = idx & 127;
    dst[idx] = (kls[t * 132 + c] - mrow[t]) * vrow[t] * l0g[c] + l0b[c] + xs[c * 68 + t + 1];
  }
}

// ================================================================ megasp v2 (unchanged):
__global__ __launch_bounds__(512, 1) void k_megasp(
    float* g0, const float* lap, const float* thT,
    const float* l1g, const float* l1b, const float* e) {
  int bt = blockIdx.x, b = bt >> 6, t = bt & 63;
  __shared__ float xts[256 * 132];
  __shared__ float scs[16 * 260];
  __shared__ float ybuf[16 * 132];
  int tid = threadIdx.x;
  size_t base = (size_t)b * (N * (size_t)TILE) + (size_t)t * 128;
  for (int idx = tid * 4; idx < 32768; idx += 2048) {
    int n = idx >> 7, c = idx & 127;
    float4 v4 = *(const float4*)&g0[base + (size_t)n * TILE + c];
    *(float4*)&xts[n * 132 + c] = v4;
  }
  __syncthreads();
  const float sc = 0.08838834764831845f;
  const float* eb = e + b * 128;
  int r = tid >> 5;
  int sg = tid & 31;
  int oc = sg * 4;
  float4 g4 = *(const float4*)&l1g[oc];
  float4 bb4 = *(const float4*)&l1b[oc];
  float4 e4 = *(const float4*)&eb[oc];
  for (int chunk = 0; chunk < 16; ++chunk) {
    int n0 = chunk * 16;
    int n = n0 + r;
    float a[8];
#pragma unroll
    for (int jj = 0; jj < 8; ++jj) a[jj] = 0.f;
    const float* qrow = &xts[n * 132];
    for (int k = 0; k < 128; k += 4) {
      float4 q4 = *(const float4*)&qrow[k];
#pragma unroll
      for (int jj = 0; jj < 8; ++jj) {
        const float4 m4 = *(const float4*)&xts[(sg + 32 * jj) * 132 + k];
        a[jj] += q4.x * m4.x + q4.y * m4.y + q4.z * m4.z + q4.w * m4.w;
      }
    }
    float mloc = -1e30f;
#pragma unroll
    for (int jj = 0; jj < 8; ++jj) { a[jj] *= sc; mloc = fmaxf(mloc, a[jj]); }
#pragma unroll
    for (int s = 16; s > 0; s >>= 1) mloc = fmaxf(mloc, __shfl_xor(mloc, s, 32));
    float ssum = 0.f;
#pragma unroll
    for (int jj = 0; jj < 8; ++jj) { a[jj] = __expf(a[jj] - mloc); ssum += a[jj]; }
#pragma unroll
    for (int s = 16; s > 0; s >>= 1) ssum += __shfl_xor(ssum, s, 32);
    float inv = sc / ssum;
    const float* lrow = &lap[n * 256];
#pragma unroll
    for (int jj = 0; jj < 8; ++jj) {
      int m = sg + 32 * jj;
      scs[r * 260 + m] = a[jj] * inv * lrow[m];
    }
    __syncthreads();
    {
      float4 acc = {0.f, 0.f, 0.f, 0.f};
      const float* srow = &scs[r * 260];
      for (int m2 = 0; m2 < 256; ++m2) {
        float w = srow[m2];
        float4 x4 = *(const float4*)&xts[m2 * 132 + oc];
        acc.x += w * x4.x; acc.y += w * x4.y; acc.z += w * x4.z; acc.w += w * x4.w;
      }
      *(float4*)&ybuf[r * 132 + oc] = acc;
    }
    __syncthreads();
    {
      float4 acc = {0.f, 0.f, 0.f, 0.f};
      const float* yrow = &ybuf[r * 132];
      for (int i = 0; i < 128; ++i) {
        float yv = yrow[i];
        float4 w4 = *(const float4*)&thT[i * 128 + oc];
        acc.x += yv * w4.x; acc.y += yv * w4.y; acc.z += yv * w4.z; acc.w += yv * w4.w;
      }
      acc.x = fmaxf(acc.x, 0.f); acc.y = fmaxf(acc.y, 0.f);
      acc.z = fmaxf(acc.z, 0.f); acc.w = fmaxf(acc.w, 0.f);
      float sps = acc.x + acc.y + acc.z + acc.w;
      float spq = acc.x * acc.x + acc.y * acc.y + acc.z * acc.z + acc.w * acc.w;
#pragma unroll
      for (int s = 16; s > 0; s >>= 1) {
        sps += __shfl_xor(sps, s, 32);
        spq += __shfl_xor(spq, s, 32);
      }
      float mm = sps * (1.f / 128.f);
      float rs = rsqrtf(spq * (1.f / 128.f) - mm * mm + 1e-5f);
      const float* xr = &xts[n * 132 + oc];
      float4 hv;
      hv.x = (acc.x - mm) * rs * g4.x + bb4.x + xr[0] + e4.x;
      hv.y = (acc.y - mm) * rs * g4.y + bb4.y + xr[1] + e4.y;
      hv.z = (acc.z - mm) * rs * g4.z + bb4.z + xr[2] + e4.z;
      hv.w = (acc.w - mm) * rs * g4.w + bb4.w + xr[3] + e4.w;
      *(float4*)&g0[base + (size_t)n * TILE + oc] = hv;
    }
    __syncthreads();
  }
}

// ================================================================ megadec v2 (512 threads, 2 blocks/CU):
__global__ __launch_bounds__(512, 2) void k_megadec(
    const float* g0, const float* dxcT, const float* dxcb,
    const float* decT, const float* decb, const float* dc1T, const float* dc1b,
    const float* dp2w, const float* dp2b, const int* flag, void* outv) {
  int bn = blockIdx.x, b = bn >> 8, n = bn & 255;
  int f32o = flag[0];
  __shared__ float hs[128 * 68];    // h [c][t+1]; later out_pre [c][t]
  __shared__ float ecs[128 * 68];   // ec [c][t+1]
  int tid = threadIdx.x;
  const float* gp = g0 + (size_t)bn * TILE;
  for (int idx = tid * 4; idx < TILE; idx += 2048) {
    int t = idx >> 7, c = idx & 127;
    float4 v4 = *(const float4*)&gp[idx];
    hs[(c + 0) * 68 + t + 1] = v4.x;
    hs[(c + 1) * 68 + t + 1] = v4.y;
    hs[(c + 2) * 68 + t + 1] = v4.z;
    hs[(c + 3) * 68 + t + 1] = v4.w;
  }
  if (tid < 128) {
    hs[tid * 68] = 0.f; hs[tid * 68 + 65] = 0.f;
    ecs[tid * 68] = 0.f; ecs[tid * 68 + 65] = 0.f;
  }
  __syncthreads();
  int cg = tid & 31, tc = tid >> 5;   // tc 0..15
  int o0 = cg * 4, t0 = tc * 4;
  // ---- ec = conv(h, dec) -> ecs [c][t+1].  4 t x 4 o.
  {
    float4 bi = *(const float4*)&decb[o0];
    float acc[4][4];
#pragma unroll
    for (int t = 0; t < 4; ++t) { acc[t][0] = bi.x; acc[t][1] = bi.y; acc[t][2] = bi.z; acc[t][3] = bi.w; }
    for (int i = 0; i < 128; ++i) {
      const float* xr = &hs[i * 68 + t0];
      float xv[6];
#pragma unroll
      for (int u = 0; u < 6; ++u) xv[u] = xr[u];
#pragma unroll
      for (int j = 0; j < 3; ++j) {
        float4 w4 = *(const float4*)&decT[(j * 128 + i) * 128 + o0];
#pragma unroll
        for (int t = 0; t < 4; ++t) {
          float xvv = xv[t + j];
          acc[t][0] += xvv * w4.x; acc[t][1] += xvv * w4.y;
          acc[t][2] += xvv * w4.z; acc[t][3] += xvv * w4.w;
        }
      }
    }
#pragma unroll
    for (int t = 0; t < 4; ++t)
#pragma unroll
      for (int z = 0; z < 4; ++z) ecs[(o0 + z) * 68 + (t0 + t) + 1] = acc[t][z];
  }
  __syncthreads();
  // ---- xh = conv(h, dxc);  c1 = conv(ec, dc1);  combine
  float accx[4][4], accc[4][4];
  {
    float4 bx = *(const float4*)&dxcb[o0];
    float4 bc = *(const float4*)&dc1b[o0];
#pragma unroll
    for (int t = 0; t < 4; ++t) {
      accx[t][0] = bx.x; accx[t][1] = bx.y; accx[t][2] = bx.z; accx[t][3] = bx.w;
      accc[t][0] = bc.x; accc[t][1] = bc.y; accc[t][2] = bc.z; accc[t][3] = bc.w;
    }
    for (int i = 0; i < 128; ++i) {
      const float* hr = &hs[i * 68 + t0];
      const float* er = &ecs[i * 68 + t0];
      float xvh[6], xvc[6];
#pragma unroll
      for (int u = 0; u < 6; ++u) { xvh[u] = hr[u]; xvc[u] = er[u]; }
#pragma unroll
      for (int j = 0; j < 3; ++j) {
        float4 wx = *(const float4*)&dxcT[(j * 128 + i) * 128 + o0];
        float4 wc = *(const float4*)&dc1T[(j * 128 + i) * 128 + o0];
#pragma unroll
        for (int t = 0; t < 4; ++t) {
          float hv = xvh[t + j], ev = xvc[t + j];
          accx[t][0] += hv * wx.x; accx[t][1] += hv * wx.y;
          accx[t][2] += hv * wx.z; accx[t][3] += hv * wx.w;
          accc[t][0] += ev * wc.x; accc[t][1] += ev * wc.y;
          accc[t][2] += ev * wc.z; accc[t][3] += ev * wc.w;
        }
      }
    }
#pragma unroll
    for (int t = 0; t < 4; ++t) {
      int row = t0 + t;
#pragma unroll
      for (int z = 0; z < 4; ++z) {
        float ecv = ecs[(o0 + z) * 68 + row + 1];
        accx[t][z] = fmaxf(accx[t][z] + sigm(ecv) + accc[t][z], 0.f);
      }
    }
  }
  __syncthreads();  // all hs reads done before overwrite
  // store out_pre into hs as [c][t]
#pragma unroll
  for (int t = 0; t < 4; ++t)
#pragma unroll
    for (int z = 0; z < 4; ++z) hs[(o0 + z) * 68 + (t0 + t)] = accx[t][z];
  __syncthreads();
  // ---- projection 128 -> 2, width-8 shuffle reduce
  int tt = tid >> 3, sg8 = tid & 7;   // 64 rows x 8 lanes
  float a0 = 0.f, a1 = 0.f;
  for (int u = 0; u < 16; ++u) {
    int c = sg8 * 16 + u;
    float v = hs[c * 68 + tt];
    a0 += v * dp2w[c];
    a1 += v * dp2w[128 + c];
  }
#pragma unroll
  for (int m = 4; m > 0; m >>= 1) {
    a0 += __shfl_xor(a0, m, 8);
    a1 += __shfl_xor(a1, m, 8);
  }
  if (sg8 == 0) {
    float o0v = a0 + dp2b[0];
    float o1v = a1 + dp2b[1];
    size_t i0 = ((size_t)(b * 2 + 0) * 256 + n) * 64 + tt;
    size_t i1 = ((size_t)(b * 2 + 1) * 256 + n) * 64 + tt;
    if (f32o) {
      ((float*)outv)[i0] = o0v;
      ((float*)outv)[i1] = o1v;
    } else {
      ((__hip_bfloat16*)outv)[i0] = __float2bfloat16(o0v);
      ((__hip_bfloat16*)outv)[i1] = __float2bfloat16(o1v);
    }
  }
}

}  // namespace

extern "C" void kernel_launch(void* const* d_in, const int* in_sizes, int n_in,
                              void* d_out, int out_size, void* d_ws, size_t ws_size,
                              hipStream_t stream) {
  (void)in_sizes; (void)n_in; (void)out_size; (void)ws_size;
  const void* x    = d_in[0];
  const void* adj  = d_in[1];
  const int*  step = (const int*)d_in[2];
  const void* wq   = d_in[3];
  const void* bq   = d_in[4];
  const void* wk   = d_in[5];
  const void* bk   = d_in[6];
  const void* w1   = d_in[7];
  const void* b1   = d_in[8];
  const void* w2   = d_in[9];
  const void* b2   = d_in[10];
  const void* th   = d_in[11];
  const void* l0g  = d_in[12];
  const void* l0b  = d_in[13];
  const void* l1g  = d_in[14];
  const void* l1b  = d_in[15];
  const void* p1w  = d_in[16];
  const void* p1b  = d_in[17];
  const void* p2w  = d_in[18];
  const void* p2b  = d_in[19];
  const void* dxcw = d_in[20];
  const void* dxcb = d_in[21];
  const void* decw = d_in[22];
  const void* decb = d_in[23];
  const void* dc1w = d_in[24];
  const void* dc1b = d_in[25];
  const void* dp2w = d_in[26];
  const void* dp2b = d_in[27];

  float* ws = (float*)d_ws;
  int* flag = (int*)ws;
  float* p = ws + 16;
  float* e     = p; p += 1024;
  float* lap   = p; p += 65536;
  float* wqkT  = p; p += 98304;
  float* w1T   = p; p += 16384;
  float* w2T   = p; p += 16384;
  float* thT   = p; p += 16384;
  float* dxcT  = p; p += 49152;
  float* decT  = p; p += 49152;
  float* dc1T  = p; p += 49152;
  float* bqk   = p; p += 256;
  float* b1f   = p; p += 128;
  float* b2f   = p; p += 128;
  float* l0gf  = p; p += 128;
  float* l0bf  = p; p += 128;
  float* l1gf  = p; p += 128;
  float* l1bf  = p; p += 128;
  float* dxcbf = p; p += 128;
  float* decbf = p; p += 128;
  float* dc1bf = p; p += 128;
  float* dp2wf = p; p += 256;
  float* dp2bf = p; p += 8;
  size_t off = (size_t)(p - ws);
  off = (off + 127) & ~(size_t)127;
  float* xf = ws + off;            // BIGE floats (67 MB)
  float* g0 = xf + BIGE;           // BIGE floats (67 MB)

  PrepArgs pa;
  pa.flag = flag;
  pa.wq = wq; pa.wk = wk; pa.w1 = w1; pa.w2 = w2; pa.th = th;
  pa.dxc = dxcw; pa.dec = decw; pa.dc1 = dc1w;
  pa.bq = bq; pa.bk = bk; pa.b1 = b1; pa.b2 = b2;
  pa.l0g = l0g; pa.l0b = l0b; pa.l1g = l1g; pa.l1b = l1b;
  pa.dxcb = dxcb; pa.decb = decb; pa.dc1b = dc1b; pa.dp2w = dp2w; pa.dp2b = dp2b;
  pa.wqkT = wqkT; pa.w1T = w1T; pa.w2T = w2T; pa.thT = thT;
  pa.dxcT = dxcT; pa.decT = decT; pa.dc1T = dc1T;
  pa.bqk = bqk; pa.b1f = b1f; pa.b2f = b2f;
  pa.l0gf = l0gf; pa.l0bf = l0bf; pa.l1gf = l1gf; pa.l1bf = l1bf;
  pa.dxcbf = dxcbf; pa.decbf = decbf; pa.dc1bf = dc1bf; pa.dp2wf = dp2wf; pa.dp2bf = dp2bf;

  k_sniff<<<1, 64, 0, stream>>>((const unsigned short*)x, flag);
  k_cvtx<<<1024, 256, 0, stream>>>(x, flag, xf);
  k_prep<<<128, 256, 0, stream>>>(pa);
  k_lap<<<1, 256, 0, stream>>>(adj, flag, lap);
  k_emb<<<8, 128, 0, stream>>>(step, flag, p1w, p1b, p2w, p2b, e);

  k_mega1<<<2048, 1024, 0, stream>>>(xf, wqkT, bqk, w1T, b1f, w2T, b2f, l0gf, l0bf, g0);
  k_megasp<<<512, 512, 0, stream>>>(g0, lap, thT, l1gf, l1bf, e);
  k_megadec<<<2048, 512, 0, stream>>>(g0, dxcT, dxcbf, decT, decbf, dc1T, dc1bf,
                                      dp2wf, dp2bf, flag, d_out);
}

// Round 7
// 1927.184 us; speedup vs baseline: 1.2395x; 1.2395x over previous
//
#include <hip/hip_runtime.h>
#include <hip/hip_bf16.h>

namespace {

constexpr int C = 128, N = 256, T = 64, Bsz = 8;
constexpr int TILE = T * C;                       // 8192 elements per (b,n) slab
constexpr size_t BIGE = (size_t)Bsz * N * T * C;  // 16,777,216 elements

__device__ __forceinline__ float bfu(unsigned short u) {
  unsigned int x = ((unsigned int)u) << 16;
  return __uint_as_float(x);
}
// flag-aware load: f32 != 0 -> input is fp32, else bf16
__device__ __forceinline__ float ld(const void* p, size_t i, int f32) {
  if (f32) return ((const float*)p)[i];
  return bfu(((const unsigned short*)p)[i]);
}
__device__ __forceinline__ float sigm(float x) { return 1.f / (1.f + __expf(-x)); }

// ---------------------------------------------------------------- dtype sniffer
__global__ __launch_bounds__(64) void k_sniff(const unsigned short* x, int* flag) {
  __shared__ int cnt[64];
  int tid = threadIdx.x;
  int c = 0;
  for (int u = 0; u < 8; ++u) {
    unsigned short v = x[tid * 8 + u];
    int e = (v >> 7) & 255;
    c += (e >= 97 && e <= 157) ? 1 : 0;
  }
  cnt[tid] = c;
  __syncthreads();
  if (tid == 0) {
    int s = 0;
    for (int i = 0; i < 64; ++i) s += cnt[i];
    flag[0] = (s < 435) ? 1 : 0;  // <85% plausible-bf16 words -> fp32 input
  }
}

// ---------------------------------------------------------------- x -> fp32 copy
__global__ __launch_bounds__(256) void k_cvtx(const void* x, const int* flag, float* xf) {
  int f = flag[0];
  size_t i0 = ((size_t)blockIdx.x * 256 + threadIdx.x) * 4;
  size_t stride = (size_t)gridDim.x * 1024;
  if (f) {
    const float4* src = (const float4*)x;
    for (size_t i = i0; i < BIGE; i += stride) *(float4*)&xf[i] = src[i >> 2];
  } else {
    const ushort4* src = (const ushort4*)x;
    for (size_t i = i0; i < BIGE; i += stride) {
      ushort4 u = src[i >> 2];
      float4 v; v.x = bfu(u.x); v.y = bfu(u.y); v.z = bfu(u.z); v.w = bfu(u.w);
      *(float4*)&xf[i] = v;
    }
  }
}

// ---------------------------------------------------------------- prep (weights -> fp32, k-major)
struct PrepArgs {
  const int* flag;
  const void *wq, *wk, *w1, *w2, *th, *dxc, *dec, *dc1;
  const void *bq, *bk, *b1, *b2, *l0g, *l0b, *l1g, *l1b, *dxcb, *decb, *dc1b, *dp2w, *dp2b;
  float *wqkT, *w1T, *w2T, *thT, *dxcT, *decT, *dc1T;
  __hip_bfloat16* thB;
  float *bqk, *b1f, *b2f, *l0gf, *l0bf, *l1gf, *l1bf, *dxcbf, *decbf, *dc1bf, *dp2wf, *dp2bf;
};

__global__ __launch_bounds__(256) void k_prep(PrepArgs a) {
  int f = a.flag[0];
  int idx = blockIdx.x * blockDim.x + threadIdx.x;
  int stride = gridDim.x * blockDim.x;
  for (int i = idx; i < 384 * 256; i += stride) {
    int k = i >> 8, o = i & 255, j = k >> 7, ii = k & 127;
    a.wqkT[i] = (o < 128) ? ld(a.wq, (o * 128 + ii) * 3 + j, f)
                          : ld(a.wk, ((o - 128) * 128 + ii) * 3 + j, f);
  }
  for (int i = idx; i < 16384; i += stride) {
    int k = i >> 7, o = i & 127;
    a.w1T[i] = ld(a.w1, o * 128 + k, f);
    a.w2T[i] = ld(a.w2, o * 128 + k, f);
    float tv = ld(a.th, o * 128 + k, f);
    a.thT[i] = tv;
    a.thB[i] = __float2bfloat16(tv);
  }
  for (int i = idx; i < 384 * 128; i += stride) {
    int k = i >> 7, o = i & 127, j = k >> 7, ii = k & 127;
    int s = (o * 128 + ii) * 3 + j;
    a.dxcT[i] = ld(a.dxc, s, f); a.decT[i] = ld(a.dec, s, f); a.dc1T[i] = ld(a.dc1, s, f);
  }
  for (int i = idx; i < 256; i += stride) {
    a.bqk[i] = (i < 128) ? ld(a.bq, i, f) : ld(a.bk, i - 128, f);
    a.dp2wf[i] = ld(a.dp2w, i, f);
  }
  for (int i = idx; i < 128; i += stride) {
    a.b1f[i] = ld(a.b1, i, f);   a.b2f[i] = ld(a.b2, i, f);
    a.l0gf[i] = ld(a.l0g, i, f); a.l0bf[i] = ld(a.l0b, i, f);
    a.l1gf[i] = ld(a.l1g, i, f); a.l1bf[i] = ld(a.l1b, i, f);
    a.dxcbf[i] = ld(a.dxcb, i, f); a.decbf[i] = ld(a.decb, i, f); a.dc1bf[i] = ld(a.dc1b, i, f);
  }
  if (idx < 2) a.dp2bf[idx] = ld(a.dp2b, idx, f);
}

__global__ __launch_bounds__(256) void k_lap(const void* adj, const int* flag, float* lap) {
  __shared__ float dsh[256];
  int f = flag[0];
  int tid = threadIdx.x;
  float s = 0.f;
  for (int m = 0; m < 256; ++m) s += ld(adj, tid * 256 + m, f);
  dsh[tid] = 1.f / sqrtf(s);
  __syncthreads();
  for (int idx = tid; idx < 65536; idx += 256) {
    int n = idx >> 8, m = idx & 255;
    lap[idx] = ld(adj, idx, f) * dsh[n] * dsh[m];
  }
}

__global__ __launch_bounds__(128) void k_emb(const int* step, const int* flag,
                                             const void* p1w, const void* p1b,
                                             const void* p2w, const void* p2b, float* e) {
  int b = blockIdx.x, c = threadIdx.x;
  int f = flag[0];
  __shared__ float tab[128], e1[128];
  float sv = (float)step[b];
  int i0 = c & 63;
  float fr = powf(10.f, (float)i0 / 63.f * 4.f);
  float ang = sv * fr;
  tab[c] = (c < 64) ? sinf(ang) : cosf(ang);
  __syncthreads();
  float a = ld(p1b, c, f);
  for (int i = 0; i < 128; ++i) a += tab[i] * ld(p1w, c * 128 + i, f);
  a = a * sigm(a);
  e1[c] = a;
  __syncthreads();
  float a2 = ld(p2b, c, f);
  for (int i = 0; i < 128; ++i) a2 += e1[i] * ld(p2w, c * 128 + i, f);
  e[b * 128 + c] = a2 * sigm(a2);
}

// ================================================================ mega1 v3 (512 threads) — round-5 proven version.
// 8t tiles, NOT 4t: at this intensity, bigger tiles beat more waves (r6 lesson).
__global__ __launch_bounds__(512, 1) void k_mega1(
    const float* xf, const float* wqkT, const float* bqk,
    const float* w1T, const float* b1f, const float* w2T, const float* b2f,
    const float* l0g, const float* l0b, float* g0) {
  int bn = blockIdx.x, b = bn >> 8, n = bn & 255;
  __shared__ float xs[128 * 68];    // x tile, [c][t+1], zero pads at tt=0,65
  __shared__ float qls[64 * 132];   // q [t][c]; later o [t][c]
  __shared__ float kls[64 * 132];   // k [t][c]; later o.w2^T [t][c]
  __shared__ float vls[64 * 132];   // v [t][c]; later o^T [c*66+t]
  __shared__ float mrow[64], vrow[64];
  int tid = threadIdx.x;
  const float* xb = xf + (size_t)b * C * N * T + (size_t)n * T;
  for (int idx = tid * 4; idx < TILE; idx += 2048) {
    int i = idx >> 6, t = idx & 63;
    float4 v4 = *(const float4*)&xb[(size_t)i * N * T + t];
    float* row = &xs[i * 68 + t + 1];
    row[0] = v4.x; row[1] = v4.y; row[2] = v4.z; row[3] = v4.w;
  }
  if (tid < 128) { xs[tid * 68] = 0.f; xs[tid * 68 + 65] = 0.f; }
  __syncthreads();
  // ---- QK conv GEMM (K=384, 256 cols) -> qls, kls.  8 t x 4 o per thread.
  {
    int cg = tid & 63, tc = tid >> 6;      // tc 0..7
    int o0 = cg * 4, t0 = tc * 8;
    float4 bi = *(const float4*)&bqk[o0];
    float acc[8][4];
#pragma unroll
    for (int t = 0; t < 8; ++t) { acc[t][0] = bi.x; acc[t][1] = bi.y; acc[t][2] = bi.z; acc[t][3] = bi.w; }
    for (int i = 0; i < 128; ++i) {
      const float* xr = &xs[i * 68 + t0];
      float xv[10];
#pragma unroll
      for (int u = 0; u < 10; ++u) xv[u] = xr[u];
#pragma unroll
      for (int j = 0; j < 3; ++j) {
        float4 w4 = *(const float4*)&wqkT[(j * 128 + i) * 256 + o0];
#pragma unroll
        for (int t = 0; t < 8; ++t) {
          float xvv = xv[t + j];
          acc[t][0] += xvv * w4.x; acc[t][1] += xvv * w4.y;
          acc[t][2] += xvv * w4.z; acc[t][3] += xvv * w4.w;
        }
      }
    }
    float* dst = (o0 < 128) ? qls : kls;
    int oo = o0 & 127;
#pragma unroll
    for (int t = 0; t < 8; ++t) {
      float4 r4; r4.x = acc[t][0]; r4.y = acc[t][1]; r4.z = acc[t][2]; r4.w = acc[t][3];
      *(float4*)&dst[(t0 + t) * 132 + oo] = r4;
    }
  }
  // ---- V GEMM (K=128) -> vls.  4 t x 4 o per thread.
  {
    int cg = tid & 31, tc = tid >> 5;      // tc 0..15
    int o0 = cg * 4, t0 = tc * 4;
    float4 bi = *(const float4*)&b1f[o0];
    float acc[4][4];
#pragma unroll
    for (int t = 0; t < 4; ++t) { acc[t][0] = bi.x; acc[t][1] = bi.y; acc[t][2] = bi.z; acc[t][3] = bi.w; }
    for (int i = 0; i < 128; ++i) {
      const float* xr = &xs[i * 68 + t0 + 1];
      float4 w4 = *(const float4*)&w1T[i * 128 + o0];
#pragma unroll
      for (int t = 0; t < 4; ++t) {
        float xv = xr[t];
        acc[t][0] += xv * w4.x; acc[t][1] += xv * w4.y; acc[t][2] += xv * w4.z; acc[t][3] += xv * w4.w;
      }
    }
#pragma unroll
    for (int t = 0; t < 4; ++t) {
      float4 r4; r4.x = acc[t][0]; r4.y = acc[t][1]; r4.z = acc[t][2]; r4.w = acc[t][3];
      *(float4*)&vls[(t0 + t) * 132 + o0] = r4;
    }
  }
  __syncthreads();
  // ---- temporal attention: 8-lane group per q-row t; heads sequential.
  {
    int t = tid >> 3;      // 0..63 (q row)
    int sg = tid & 7;      // lane in row-group
    for (int h = 0; h < 8; ++h) {
      int hb = h * 16;
      float4 q0 = *(const float4*)&qls[t * 132 + hb];
      float4 q1 = *(const float4*)&qls[t * 132 + hb + 4];
      float4 q2 = *(const float4*)&qls[t * 132 + hb + 8];
      float4 q3 = *(const float4*)&qls[t * 132 + hb + 12];
      float a[8];
#pragma unroll
      for (int j = 0; j < 8; ++j) {
        int s = sg + 8 * j;
        const float* kr = &kls[s * 132 + hb];
        float4 k0 = *(const float4*)&kr[0];
        float4 k1 = *(const float4*)&kr[4];
        float4 k2 = *(const float4*)&kr[8];
        float4 k3 = *(const float4*)&kr[12];
        a[j] = (q0.x * k0.x + q0.y * k0.y + q0.z * k0.z + q0.w * k0.w +
                q1.x * k1.x + q1.y * k1.y + q1.z * k1.z + q1.w * k1.w +
                q2.x * k2.x + q2.y * k2.y + q2.z * k2.z + q2.w * k2.w +
                q3.x * k3.x + q3.y * k3.y + q3.z * k3.z + q3.w * k3.w) * 0.25f;
      }
      float mx = a[0];
#pragma unroll
      for (int j = 1; j < 8; ++j) mx = fmaxf(mx, a[j]);
#pragma unroll
      for (int m = 4; m > 0; m >>= 1) mx = fmaxf(mx, __shfl_xor(mx, m, 8));
      float sum = 0.f;
#pragma unroll
      for (int j = 0; j < 8; ++j) { a[j] = __expf(a[j] - mx); sum += a[j]; }
#pragma unroll
      for (int m = 4; m > 0; m >>= 1) sum += __shfl_xor(sum, m, 8);
      float inv = 1.f / sum;
#pragma unroll
      for (int j = 0; j < 8; ++j) a[j] *= inv;
      float o[16];
#pragma unroll
      for (int d = 0; d < 16; ++d) o[d] = 0.f;
#pragma unroll
      for (int j = 0; j < 8; ++j) {
        int s = sg + 8 * j;
        const float* vr = &vls[s * 132 + hb];
        float w = a[j];
#pragma unroll
        for (int d = 0; d < 16; ++d) o[d] += w * vr[d];
      }
#pragma unroll
      for (int m = 4; m > 0; m >>= 1)
#pragma unroll
        for (int d = 0; d < 16; ++d) o[d] += __shfl_xor(o[d], m, 8);
      if (sg < 4) {
        float4 r4;
        r4.x = o[sg * 4 + 0]; r4.y = o[sg * 4 + 1];
        r4.z = o[sg * 4 + 2]; r4.w = o[sg * 4 + 3];
        *(float4*)&qls[t * 132 + hb + sg * 4] = r4;
      }
    }
  }
  __syncthreads();
  // ---- transpose o -> tr (reuse vls as [c*66 + t])
  float* tr = vls;
  for (int idx = tid; idx < TILE; idx += 512) {
    int t = idx >> 7, c = idx & 127;
    tr[c * 66 + t] = qls[t * 132 + c];
  }
  __syncthreads();
  // ---- w2 GEMM: ls[t][o] = sum_i o[t][i]*w2[o][i] + b2 -> kls. 4 t x 4 o.
  {
    int cg = tid & 31, tc = tid >> 5;
    int o0 = cg * 4, t0 = tc * 4;
    float4 bi = *(const float4*)&b2f[o0];
    float acc[4][4];
#pragma unroll
    for (int t = 0; t < 4; ++t) { acc[t][0] = bi.x; acc[t][1] = bi.y; acc[t][2] = bi.z; acc[t][3] = bi.w; }
    for (int i = 0; i < 128; ++i) {
      const float* xr = &tr[i * 66 + t0];
      float4 w4 = *(const float4*)&w2T[i * 128 + o0];
#pragma unroll
      for (int t = 0; t < 4; ++t) {
        float xv = xr[t];
        acc[t][0] += xv * w4.x; acc[t][1] += xv * w4.y; acc[t][2] += xv * w4.z; acc[t][3] += xv * w4.w;
      }
    }
#pragma unroll
    for (int t = 0; t < 4; ++t) {
      float4 r4; r4.x = acc[t][0]; r4.y = acc[t][1]; r4.z = acc[t][2]; r4.w = acc[t][3];
      *(float4*)&kls[(t0 + t) * 132 + o0] = r4;
    }
  }
  __syncthreads();
  // ---- LN0 stats via shuffles: 8-lane group per row
  {
    int r = tid >> 3, sg = tid & 7;
    float s = 0.f, q2 = 0.f;
    const float* row = &kls[r * 132 + sg * 16];
    for (int u = 0; u < 16; ++u) {
      float v = row[u];
      s += v; q2 += v * v;
    }
#pragma unroll
    for (int m = 4; m > 0; m >>= 1) {
      s += __shfl_xor(s, m, 8);
      q2 += __shfl_xor(q2, m, 8);
    }
    if (sg == 0) {
      float mm = s * (1.f / 128.f);
      mrow[r] = mm;
      vrow[r] = rsqrtf(q2 * (1.f / 128.f) - mm * mm + 1e-5f);
    }
  }
  __syncthreads();
  float* dst = g0 + (size_t)bn * TILE;
  for (int idx = tid; idx < TILE; idx += 512) {
    int t = idx >> 7, c = idx & 127;
    dst[idx] = (kls[t * 132 + c] - mrow[t]) * vrow[t] * l0g[c] + l0b[c] + xs[c * 68 + t + 1];
  }
}

// ================================================================ megasp v3:
// per (b,t): spatial attention scores + softmax (registers) + lap weighting +
// PV.  Writes y (B,T,N,C contiguous) to yout; theta/LN1 moved to k_theta.
__global__ __launch_bounds__(512, 1) void k_megasp(
    const float* g0, const float* lap, float* yout) {
  int bt = blockIdx.x, b = bt >> 6, t = bt & 63;
  __shared__ float xts[256 * 132];  // 135168 B  (xp slab, [n][c])
  __shared__ float scs[16 * 260];   // 16640 B   (weighted attention, one chunk)
  int tid = threadIdx.x;
  size_t base = (size_t)b * (N * (size_t)TILE) + (size_t)t * 128;
  for (int idx = tid * 4; idx < 32768; idx += 2048) {
    int n = idx >> 7, c = idx & 127;
    float4 v4 = *(const float4*)&g0[base + (size_t)n * TILE + c];
    *(float4*)&xts[n * 132 + c] = v4;
  }
  __syncthreads();
  const float sc = 0.08838834764831845f;  // 1/sqrt(128)
  int r = tid >> 5;          // 0..15 (row within chunk)
  int sg = tid & 31;         // lane-in-row
  int oc = sg * 4;
  float* yb = yout + (size_t)bt * 32768;
  for (int chunk = 0; chunk < 16; ++chunk) {
    int n0 = chunk * 16;
    int n = n0 + r;
    float a[8];
#pragma unroll
    for (int jj = 0; jj < 8; ++jj) a[jj] = 0.f;
    const float* qrow = &xts[n * 132];
    for (int k = 0; k < 128; k += 4) {
      float4 q4 = *(const float4*)&qrow[k];
#pragma unroll
      for (int jj = 0; jj < 8; ++jj) {
        const float4 m4 = *(const float4*)&xts[(sg + 32 * jj) * 132 + k];
        a[jj] += q4.x * m4.x + q4.y * m4.y + q4.z * m4.z + q4.w * m4.w;
      }
    }
    float mloc = -1e30f;
#pragma unroll
    for (int jj = 0; jj < 8; ++jj) { a[jj] *= sc; mloc = fmaxf(mloc, a[jj]); }
#pragma unroll
    for (int s = 16; s > 0; s >>= 1) mloc = fmaxf(mloc, __shfl_xor(mloc, s, 32));
    float ssum = 0.f;
#pragma unroll
    for (int jj = 0; jj < 8; ++jj) { a[jj] = __expf(a[jj] - mloc); ssum += a[jj]; }
#pragma unroll
    for (int s = 16; s > 0; s >>= 1) ssum += __shfl_xor(ssum, s, 32);
    float inv = sc / ssum;   // softmax * sc folded
    const float* lrow = &lap[n * 256];
#pragma unroll
    for (int jj = 0; jj < 8; ++jj) {
      int m = sg + 32 * jj;
      scs[r * 260 + m] = a[jj] * inv * lrow[m];
    }
    __syncthreads();
    // ---- PV -> y (global, coalesced)
    {
      float4 acc = {0.f, 0.f, 0.f, 0.f};
      const float* srow = &scs[r * 260];
      for (int m2 = 0; m2 < 256; ++m2) {
        float w = srow[m2];
        float4 x4 = *(const float4*)&xts[m2 * 132 + oc];
        acc.x += w * x4.x; acc.y += w * x4.y; acc.z += w * x4.z; acc.w += w * x4.w;
      }
      *(float4*)&yb[(size_t)n * 128 + oc] = acc;
    }
    __syncthreads();   // protect scs before next chunk
  }
}

// ================================================================ k_theta (new):
// per (b,t): h[n,:] = xp[n,:] + LN1(relu(y[n,:] . theta^T)) + e, written IN
// PLACE over xp in g0.  Theta staged once per block in LDS as bf16 (32 KB) --
// kills the 16 MB/block L2 re-streaming megasp was paying.
__global__ __launch_bounds__(512, 4) void k_theta(
    const float* y, const unsigned short* thB, float* g0,
    const float* l1g, const float* l1b, const float* e) {
  int bt = blockIdx.x, b = bt >> 6, t = bt & 63;
  __shared__ unsigned short ths[16384];  // theta bf16, [k*128 + o]  (32 KB)
  __shared__ float ybuf[32 * 132];       // 16.9 KB
  int tid = threadIdx.x;
  for (int idx = tid * 8; idx < 16384; idx += 4096)
    *(uint4*)&ths[idx] = *(const uint4*)&thB[idx];
  int r = tid >> 4;       // 0..31 (row within chunk)
  int sg = tid & 15;
  int oc = sg * 8;
  const float* eb = e + b * 128;
  float gg[8], bb[8], ev[8];
#pragma unroll
  for (int u = 0; u < 8; ++u) { gg[u] = l1g[oc + u]; bb[u] = l1b[oc + u]; ev[u] = eb[oc + u]; }
  const float* ybase = y + (size_t)bt * 32768;
  __syncthreads();
  for (int chunk = 0; chunk < 8; ++chunk) {
    int n0 = chunk * 32;
    for (int idx = tid * 4; idx < 4096; idx += 2048) {
      int rr = idx >> 7, c = idx & 127;
      *(float4*)&ybuf[rr * 132 + c] = *(const float4*)&ybase[(size_t)(n0 + rr) * 128 + c];
    }
    __syncthreads();
    float acc[8];
#pragma unroll
    for (int u = 0; u < 8; ++u) acc[u] = 0.f;
    const float* yrow = &ybuf[r * 132];
    for (int i = 0; i < 128; ++i) {
      float yv = yrow[i];
      uint4 w = *(const uint4*)&ths[i * 128 + oc];
      float w0 = __uint_as_float(w.x << 16);
      float w1 = __uint_as_float(w.x & 0xffff0000u);
      float w2 = __uint_as_float(w.y << 16);
      float w3 = __uint_as_float(w.y & 0xffff0000u);
      float w4 = __uint_as_float(w.z << 16);
      float w5 = __uint_as_float(w.z & 0xffff0000u);
      float w6 = __uint_as_float(w.w << 16);
      float w7 = __uint_as_float(w.w & 0xffff0000u);
      acc[0] += yv * w0; acc[1] += yv * w1; acc[2] += yv * w2; acc[3] += yv * w3;
      acc[4] += yv * w4; acc[5] += yv * w5; acc[6] += yv * w6; acc[7] += yv * w7;
    }
    float sps = 0.f, spq = 0.f;
#pragma unroll
    for (int u = 0; u < 8; ++u) {
      acc[u] = fmaxf(acc[u], 0.f);
      sps += acc[u]; spq += acc[u] * acc[u];
    }
#pragma unroll
    for (int m = 8; m > 0; m >>= 1) {
      sps += __shfl_xor(sps, m, 16);
      spq += __shfl_xor(spq, m, 16);
    }
    float mm = sps * (1.f / 128.f);
    float rs = rsqrtf(spq * (1.f / 128.f) - mm * mm + 1e-5f);
    int n = n0 + r;
    size_t ga = ((size_t)(b * 256 + n)) * TILE + (size_t)t * 128 + oc;
    float4 xa = *(const float4*)&g0[ga];
    float4 xb4 = *(const float4*)&g0[ga + 4];
    float4 h0, h1;
    h0.x = (acc[0] - mm) * rs * gg[0] + bb[0] + xa.x + ev[0];
    h0.y = (acc[1] - mm) * rs * gg[1] + bb[1] + xa.y + ev[1];
    h0.z = (acc[2] - mm) * rs * gg[2] + bb[2] + xa.z + ev[2];
    h0.w = (acc[3] - mm) * rs * gg[3] + bb[3] + xa.w + ev[3];
    h1.x = (acc[4] - mm) * rs * gg[4] + bb[4] + xb4.x + ev[4];
    h1.y = (acc[5] - mm) * rs * gg[5] + bb[5] + xb4.y + ev[5];
    h1.z = (acc[6] - mm) * rs * gg[6] + bb[6] + xb4.z + ev[6];
    h1.w = (acc[7] - mm) * rs * gg[7] + bb[7] + xb4.w + ev[7];
    *(float4*)&g0[ga] = h0;
    *(float4*)&g0[ga + 4] = h1;
    __syncthreads();   // protect ybuf before restage
  }
}

// ================================================================ megadec — round-5 proven version (256 thr, 8t tiles).
__global__ __launch_bounds__(256, 2) void k_megadec(
    const float* g0, const float* dxcT, const float* dxcb,
    const float* decT, const float* decb, const float* dc1T, const float* dc1b,
    const float* dp2w, const float* dp2b, const int* flag, void* outv) {
  int bn = blockIdx.x, b = bn >> 8, n = bn & 255;
  int f32o = flag[0];
  __shared__ float hs[128 * 68];
  __shared__ float ecs[128 * 68];
  __shared__ float p0[256], p1[256];
  int tid = threadIdx.x;
  const float* gp = g0 + (size_t)bn * TILE;
  for (int idx = tid * 4; idx < TILE; idx += 1024) {
    int t = idx >> 7, c = idx & 127;
    float4 v4 = *(const float4*)&gp[idx];
    hs[(c + 0) * 68 + t + 1] = v4.x;
    hs[(c + 1) * 68 + t + 1] = v4.y;
    hs[(c + 2) * 68 + t + 1] = v4.z;
    hs[(c + 3) * 68 + t + 1] = v4.w;
  }
  if (tid < 128) {
    hs[tid * 68] = 0.f; hs[tid * 68 + 65] = 0.f;
    ecs[tid * 68] = 0.f; ecs[tid * 68 + 65] = 0.f;
  }
  __syncthreads();
  int cg = tid & 31, tc = tid >> 5;
  int o0 = cg * 4, t0 = tc * 8;
  {
    float4 bi = *(const float4*)&decb[o0];
    float acc[8][4];
#pragma unroll
    for (int t = 0; t < 8; ++t) { acc[t][0] = bi.x; acc[t][1] = bi.y; acc[t][2] = bi.z; acc[t][3] = bi.w; }
    for (int i = 0; i < 128; ++i) {
      const float* xr = &hs[i * 68 + t0];
      float xv[10];
#pragma unroll
      for (int u = 0; u < 10; ++u) xv[u] = xr[u];
#pragma unroll
      for (int j = 0; j < 3; ++j) {
        float4 w4 = *(const float4*)&decT[(j * 128 + i) * 128 + o0];
#pragma unroll
        for (int t = 0; t < 8; ++t) {
          float xvv = xv[t + j];
          acc[t][0] += xvv * w4.x; acc[t][1] += xvv * w4.y;
          acc[t][2] += xvv * w4.z; acc[t][3] += xvv * w4.w;
        }
      }
    }
#pragma unroll
    for (int t = 0; t < 8; ++t)
#pragma unroll
      for (int z = 0; z < 4; ++z) ecs[(o0 + z) * 68 + (t0 + t) + 1] = acc[t][z];
  }
  __syncthreads();
  float accx[8][4], accc[8][4];
  {
    float4 bx = *(const float4*)&dxcb[o0];
    float4 bc = *(const float4*)&dc1b[o0];
#pragma unroll
    for (int t = 0; t < 8; ++t) {
      accx[t][0] = bx.x; accx[t][1] = bx.y; accx[t][2] = bx.z; accx[t][3] = bx.w;
      accc[t][0] = bc.x; accc[t][1] = bc.y; accc[t][2] = bc.z; accc[t][3] = bc.w;
    }
    for (int i = 0; i < 128; ++i) {
      const float* hr = &hs[i * 68 + t0];
      const float* er = &ecs[i * 68 + t0];
      float xvh[10], xvc[10];
#pragma unroll
      for (int u = 0; u < 10; ++u) { xvh[u] = hr[u]; xvc[u] = er[u]; }
#pragma unroll
      for (int j = 0; j < 3; ++j) {
        float4 wx = *(const float4*)&dxcT[(j * 128 + i) * 128 + o0];
        float4 wc = *(const float4*)&dc1T[(j * 128 + i) * 128 + o0];
#pragma unroll
        for (int t = 0; t < 8; ++t) {
          float hv = xvh[t + j], ev = xvc[t + j];
          accx[t][0] += hv * wx.x; accx[t][1] += hv * wx.y;
          accx[t][2] += hv * wx.z; accx[t][3] += hv * wx.w;
          accc[t][0] += ev * wc.x; accc[t][1] += ev * wc.y;
          accc[t][2] += ev * wc.z; accc[t][3] += ev * wc.w;
        }
      }
    }
#pragma unroll
    for (int t = 0; t < 8; ++t) {
      int row = t0 + t;
#pragma unroll
      for (int z = 0; z < 4; ++z) {
        float ecv = ecs[(o0 + z) * 68 + row + 1];
        accx[t][z] = fmaxf(accx[t][z] + sigm(ecv) + accc[t][z], 0.f);
      }
    }
  }
  __syncthreads();
#pragma unroll
  for (int t = 0; t < 8; ++t)
#pragma unroll
    for (int z = 0; z < 4; ++z) hs[(o0 + z) * 68 + (t0 + t)] = accx[t][z];
  __syncthreads();
  int tt = tid >> 2, sg4 = tid & 3;
  float a0 = 0.f, a1 = 0.f;
  for (int u = 0; u < 32; ++u) {
    int c = sg4 * 32 + u;
    float v = hs[c * 68 + tt];
    a0 += v * dp2w[c];
    a1 += v * dp2w[128 + c];
  }
  p0[tid] = a0; p1[tid] = a1;
  __syncthreads();
  if (sg4 == 0) {
    float o0v = p0[tid] + p0[tid + 1] + p0[tid + 2] + p0[tid + 3] + dp2b[0];
    float o1v = p1[tid] + p1[tid + 1] + p1[tid + 2] + p1[tid + 3] + dp2b[1];
    size_t i0 = ((size_t)(b * 2 + 0) * 256 + n) * 64 + tt;
    size_t i1 = ((size_t)(b * 2 + 1) * 256 + n) * 64 + tt;
    if (f32o) {
      ((float*)outv)[i0] = o0v;
      ((float*)outv)[i1] = o1v;
    } else {
      ((__hip_bfloat16*)outv)[i0] = __float2bfloat16(o0v);
      ((__hip_bfloat16*)outv)[i1] = __float2bfloat16(o1v);
    }
  }
}

}  // namespace

extern "C" void kernel_launch(void* const* d_in, const int* in_sizes, int n_in,
                              void* d_out, int out_size, void* d_ws, size_t ws_size,
                              hipStream_t stream) {
  (void)in_sizes; (void)n_in; (void)out_size; (void)ws_size;
  const void* x    = d_in[0];
  const void* adj  = d_in[1];
  const int*  step = (const int*)d_in[2];
  const void* wq   = d_in[3];
  const void* bq   = d_in[4];
  const void* wk   = d_in[5];
  const void* bk   = d_in[6];
  const void* w1   = d_in[7];
  const void* b1   = d_in[8];
  const void* w2   = d_in[9];
  const void* b2   = d_in[10];
  const void* th   = d_in[11];
  const void* l0g  = d_in[12];
  const void* l0b  = d_in[13];
  const void* l1g  = d_in[14];
  const void* l1b  = d_in[15];
  const void* p1w  = d_in[16];
  const void* p1b  = d_in[17];
  const void* p2w  = d_in[18];
  const void* p2b  = d_in[19];
  const void* dxcw = d_in[20];
  const void* dxcb = d_in[21];
  const void* decw = d_in[22];
  const void* decb = d_in[23];
  const void* dc1w = d_in[24];
  const void* dc1b = d_in[25];
  const void* dp2w = d_in[26];
  const void* dp2b = d_in[27];

  float* ws = (float*)d_ws;
  int* flag = (int*)ws;
  float* p = ws + 16;
  float* e     = p; p += 1024;
  float* lap   = p; p += 65536;
  float* wqkT  = p; p += 98304;
  float* w1T   = p; p += 16384;
  float* w2T   = p; p += 16384;
  float* thT   = p; p += 16384;
  float* thBv  = p; p += 8192;    // 16384 bf16
  float* dxcT  = p; p += 49152;
  float* decT  = p; p += 49152;
  float* dc1T  = p; p += 49152;
  float* bqk   = p; p += 256;
  float* b1f   = p; p += 128;
  float* b2f   = p; p += 128;
  float* l0gf  = p; p += 128;
  float* l0bf  = p; p += 128;
  float* l1gf  = p; p += 128;
  float* l1bf  = p; p += 128;
  float* dxcbf = p; p += 128;
  float* decbf = p; p += 128;
  float* dc1bf = p; p += 128;
  float* dp2wf = p; p += 256;
  float* dp2bf = p; p += 8;
  size_t off = (size_t)(p - ws);
  off = (off + 127) & ~(size_t)127;
  float* xf = ws + off;            // BIGE floats (67 MB); y overwrites after mega1
  float* g0 = xf + BIGE;           // BIGE floats (67 MB)

  PrepArgs pa;
  pa.flag = flag;
  pa.wq = wq; pa.wk = wk; pa.w1 = w1; pa.w2 = w2; pa.th = th;
  pa.dxc = dxcw; pa.dec = decw; pa.dc1 = dc1w;
  pa.bq = bq; pa.bk = bk; pa.b1 = b1; pa.b2 = b2;
  pa.l0g = l0g; pa.l0b = l0b; pa.l1g = l1g; pa.l1b = l1b;
  pa.dxcb = dxcb; pa.decb = decb; pa.dc1b = dc1b; pa.dp2w = dp2w; pa.dp2b = dp2b;
  pa.wqkT = wqkT; pa.w1T = w1T; pa.w2T = w2T; pa.thT = thT;
  pa.thB = (__hip_bfloat16*)thBv;
  pa.dxcT = dxcT; pa.decT = decT; pa.dc1T = dc1T;
  pa.bqk = bqk; pa.b1f = b1f; pa.b2f = b2f;
  pa.l0gf = l0gf; pa.l0bf = l0bf; pa.l1gf = l1gf; pa.l1bf = l1bf;
  pa.dxcbf = dxcbf; pa.decbf = decbf; pa.dc1bf = dc1bf; pa.dp2wf = dp2wf; pa.dp2bf = dp2bf;

  k_sniff<<<1, 64, 0, stream>>>((const unsigned short*)x, flag);
  k_cvtx<<<1024, 256, 0, stream>>>(x, flag, xf);
  k_prep<<<128, 256, 0, stream>>>(pa);
  k_lap<<<1, 256, 0, stream>>>(adj, flag, lap);
  k_emb<<<8, 128, 0, stream>>>(step, flag, p1w, p1b, p2w, p2b, e);

  k_mega1<<<2048, 512, 0, stream>>>(xf, wqkT, bqk, w1T, b1f, w2T, b2f, l0gf, l0bf, g0);
  k_megasp<<<512, 512, 0, stream>>>(g0, lap, xf);               // y -> xf (x dead)
  k_theta<<<512, 512, 0, stream>>>(xf, (const unsigned short*)thBv, g0, l1gf, l1bf, e);
  k_megadec<<<2048, 256, 0, stream>>>(g0, dxcT, dxcbf, decT, decbf, dc1T, dc1bf,
                                      dp2wf, dp2bf, flag, d_out);
}

// Round 8
// 1518.942 us; speedup vs baseline: 1.5726x; 1.2688x over previous
//
#include <hip/hip_runtime.h>
#include <hip/hip_bf16.h>

namespace {

constexpr int C = 128, N = 256, T = 64, Bsz = 8;
constexpr int TILE = T * C;                       // 8192 elements per (b,n) slab
constexpr size_t BIGE = (size_t)Bsz * N * T * C;  // 16,777,216 elements

typedef short v8s __attribute__((ext_vector_type(8)));
typedef float v4f __attribute__((ext_vector_type(4)));

__device__ __forceinline__ float bfu(unsigned short u) {
  unsigned int x = ((unsigned int)u) << 16;
  return __uint_as_float(x);
}
__device__ __forceinline__ unsigned short f2b(float v) {
  __hip_bfloat16 h = __float2bfloat16(v);
  return *(unsigned short*)&h;
}
// flag-aware load: f32 != 0 -> input is fp32, else bf16
__device__ __forceinline__ float ld(const void* p, size_t i, int f32) {
  if (f32) return ((const float*)p)[i];
  return bfu(((const unsigned short*)p)[i]);
}
__device__ __forceinline__ float sigm(float x) { return 1.f / (1.f + __expf(-x)); }

// ---------------------------------------------------------------- dtype sniffer
__global__ __launch_bounds__(64) void k_sniff(const unsigned short* x, int* flag) {
  __shared__ int cnt[64];
  int tid = threadIdx.x;
  int c = 0;
  for (int u = 0; u < 8; ++u) {
    unsigned short v = x[tid * 8 + u];
    int e = (v >> 7) & 255;
    c += (e >= 97 && e <= 157) ? 1 : 0;
  }
  cnt[tid] = c;
  __syncthreads();
  if (tid == 0) {
    int s = 0;
    for (int i = 0; i < 64; ++i) s += cnt[i];
    flag[0] = (s < 435) ? 1 : 0;  // <85% plausible-bf16 words -> fp32 input
  }
}

// ---------------------------------------------------------------- x -> fp32 copy
__global__ __launch_bounds__(256) void k_cvtx(const void* x, const int* flag, float* xf) {
  int f = flag[0];
  size_t i0 = ((size_t)blockIdx.x * 256 + threadIdx.x) * 4;
  size_t stride = (size_t)gridDim.x * 1024;
  if (f) {
    const float4* src = (const float4*)x;
    for (size_t i = i0; i < BIGE; i += stride) *(float4*)&xf[i] = src[i >> 2];
  } else {
    const ushort4* src = (const ushort4*)x;
    for (size_t i = i0; i < BIGE; i += stride) {
      ushort4 u = src[i >> 2];
      float4 v; v.x = bfu(u.x); v.y = bfu(u.y); v.z = bfu(u.z); v.w = bfu(u.w);
      *(float4*)&xf[i] = v;
    }
  }
}

// ---------------------------------------------------------------- prep (weights -> fp32 k-major; decoder -> bf16 [o][k])
struct PrepArgs {
  const int* flag;
  const void *wq, *wk, *w1, *w2, *th, *dxc, *dec, *dc1;
  const void *bq, *bk, *b1, *b2, *l0g, *l0b, *l1g, *l1b, *dxcb, *decb, *dc1b, *dp2w, *dp2b;
  float *wqkT, *w1T, *w2T, *thT;
  __hip_bfloat16* thB;
  unsigned short *decWb, *dxcWb, *dc1Wb;   // bf16 [o][k], k = j*128+i
  float *bqk, *b1f, *b2f, *l0gf, *l0bf, *l1gf, *l1bf, *dxcbf, *decbf, *dc1bf, *dp2wf, *dp2bf;
};

__global__ __launch_bounds__(256) void k_prep(PrepArgs a) {
  int f = a.flag[0];
  int idx = blockIdx.x * blockDim.x + threadIdx.x;
  int stride = gridDim.x * blockDim.x;
  for (int i = idx; i < 384 * 256; i += stride) {
    int k = i >> 8, o = i & 255, j = k >> 7, ii = k & 127;
    a.wqkT[i] = (o < 128) ? ld(a.wq, (o * 128 + ii) * 3 + j, f)
                          : ld(a.wk, ((o - 128) * 128 + ii) * 3 + j, f);
  }
  for (int i = idx; i < 16384; i += stride) {
    int k = i >> 7, o = i & 127;
    a.w1T[i] = ld(a.w1, o * 128 + k, f);
    a.w2T[i] = ld(a.w2, o * 128 + k, f);
    float tv = ld(a.th, o * 128 + k, f);
    a.thT[i] = tv;
    a.thB[i] = __float2bfloat16(tv);
  }
  // decoder conv weights -> bf16 [o][k = j*128 + ii]
  for (int i = idx; i < 16384; i += stride) {
    int o = i >> 7, ii = i & 127;
    int sbase = (o * 128 + ii) * 3;
#pragma unroll
    for (int j = 0; j < 3; ++j) {
      int dsti = o * 384 + j * 128 + ii;
      a.decWb[dsti] = f2b(ld(a.dec, sbase + j, f));
      a.dxcWb[dsti] = f2b(ld(a.dxc, sbase + j, f));
      a.dc1Wb[dsti] = f2b(ld(a.dc1, sbase + j, f));
    }
  }
  for (int i = idx; i < 256; i += stride) {
    a.bqk[i] = (i < 128) ? ld(a.bq, i, f) : ld(a.bk, i - 128, f);
    a.dp2wf[i] = ld(a.dp2w, i, f);
  }
  for (int i = idx; i < 128; i += stride) {
    a.b1f[i] = ld(a.b1, i, f);   a.b2f[i] = ld(a.b2, i, f);
    a.l0gf[i] = ld(a.l0g, i, f); a.l0bf[i] = ld(a.l0b, i, f);
    a.l1gf[i] = ld(a.l1g, i, f); a.l1bf[i] = ld(a.l1b, i, f);
    a.dxcbf[i] = ld(a.dxcb, i, f); a.decbf[i] = ld(a.decb, i, f); a.dc1bf[i] = ld(a.dc1b, i, f);
  }
  if (idx < 2) a.dp2bf[idx] = ld(a.dp2b, idx, f);
}

__global__ __launch_bounds__(256) void k_lap(const void* adj, const int* flag, float* lap) {
  __shared__ float dsh[256];
  int f = flag[0];
  int tid = threadIdx.x;
  float s = 0.f;
  for (int m = 0; m < 256; ++m) s += ld(adj, tid * 256 + m, f);
  dsh[tid] = 1.f / sqrtf(s);
  __syncthreads();
  for (int idx = tid; idx < 65536; idx += 256) {
    int n = idx >> 8, m = idx & 255;
    lap[idx] = ld(adj, idx, f) * dsh[n] * dsh[m];
  }
}

__global__ __launch_bounds__(128) void k_emb(const int* step, const int* flag,
                                             const void* p1w, const void* p1b,
                                             const void* p2w, const void* p2b, float* e) {
  int b = blockIdx.x, c = threadIdx.x;
  int f = flag[0];
  __shared__ float tab[128], e1[128];
  float sv = (float)step[b];
  int i0 = c & 63;
  float fr = powf(10.f, (float)i0 / 63.f * 4.f);
  float ang = sv * fr;
  tab[c] = (c < 64) ? sinf(ang) : cosf(ang);
  __syncthreads();
  float a = ld(p1b, c, f);
  for (int i = 0; i < 128; ++i) a += tab[i] * ld(p1w, c * 128 + i, f);
  a = a * sigm(a);
  e1[c] = a;
  __syncthreads();
  float a2 = ld(p2b, c, f);
  for (int i = 0; i < 128; ++i) a2 += e1[i] * ld(p2w, c * 128 + i, f);
  e[b * 128 + c] = a2 * sigm(a2);
}

// ================================================================ mega1 v3 (512 threads) — round-5 proven version.
__global__ __launch_bounds__(512, 1) void k_mega1(
    const float* xf, const float* wqkT, const float* bqk,
    const float* w1T, const float* b1f, const float* w2T, const float* b2f,
    const float* l0g, const float* l0b, float* g0) {
  int bn = blockIdx.x, b = bn >> 8, n = bn & 255;
  __shared__ float xs[128 * 68];
  __shared__ float qls[64 * 132];
  __shared__ float kls[64 * 132];
  __shared__ float vls[64 * 132];
  __shared__ float mrow[64], vrow[64];
  int tid = threadIdx.x;
  const float* xb = xf + (size_t)b * C * N * T + (size_t)n * T;
  for (int idx = tid * 4; idx < TILE; idx += 2048) {
    int i = idx >> 6, t = idx & 63;
    float4 v4 = *(const float4*)&xb[(size_t)i * N * T + t];
    float* row = &xs[i * 68 + t + 1];
    row[0] = v4.x; row[1] = v4.y; row[2] = v4.z; row[3] = v4.w;
  }
  if (tid < 128) { xs[tid * 68] = 0.f; xs[tid * 68 + 65] = 0.f; }
  __syncthreads();
  {
    int cg = tid & 63, tc = tid >> 6;
    int o0 = cg * 4, t0 = tc * 8;
    float4 bi = *(const float4*)&bqk[o0];
    float acc[8][4];
#pragma unroll
    for (int t = 0; t < 8; ++t) { acc[t][0] = bi.x; acc[t][1] = bi.y; acc[t][2] = bi.z; acc[t][3] = bi.w; }
    for (int i = 0; i < 128; ++i) {
      const float* xr = &xs[i * 68 + t0];
      float xv[10];
#pragma unroll
      for (int u = 0; u < 10; ++u) xv[u] = xr[u];
#pragma unroll
      for (int j = 0; j < 3; ++j) {
        float4 w4 = *(const float4*)&wqkT[(j * 128 + i) * 256 + o0];
#pragma unroll
        for (int t = 0; t < 8; ++t) {
          float xvv = xv[t + j];
          acc[t][0] += xvv * w4.x; acc[t][1] += xvv * w4.y;
          acc[t][2] += xvv * w4.z; acc[t][3] += xvv * w4.w;
        }
      }
    }
    float* dst = (o0 < 128) ? qls : kls;
    int oo = o0 & 127;
#pragma unroll
    for (int t = 0; t < 8; ++t) {
      float4 r4; r4.x = acc[t][0]; r4.y = acc[t][1]; r4.z = acc[t][2]; r4.w = acc[t][3];
      *(float4*)&dst[(t0 + t) * 132 + oo] = r4;
    }
  }
  {
    int cg = tid & 31, tc = tid >> 5;
    int o0 = cg * 4, t0 = tc * 4;
    float4 bi = *(const float4*)&b1f[o0];
    float acc[4][4];
#pragma unroll
    for (int t = 0; t < 4; ++t) { acc[t][0] = bi.x; acc[t][1] = bi.y; acc[t][2] = bi.z; acc[t][3] = bi.w; }
    for (int i = 0; i < 128; ++i) {
      const float* xr = &xs[i * 68 + t0 + 1];
      float4 w4 = *(const float4*)&w1T[i * 128 + o0];
#pragma unroll
      for (int t = 0; t < 4; ++t) {
        float xv = xr[t];
        acc[t][0] += xv * w4.x; acc[t][1] += xv * w4.y; acc[t][2] += xv * w4.z; acc[t][3] += xv * w4.w;
      }
    }
#pragma unroll
    for (int t = 0; t < 4; ++t) {
      float4 r4; r4.x = acc[t][0]; r4.y = acc[t][1]; r4.z = acc[t][2]; r4.w = acc[t][3];
      *(float4*)&vls[(t0 + t) * 132 + o0] = r4;
    }
  }
  __syncthreads();
  {
    int t = tid >> 3;
    int sg = tid & 7;
    for (int h = 0; h < 8; ++h) {
      int hb = h * 16;
      float4 q0 = *(const float4*)&qls[t * 132 + hb];
      float4 q1 = *(const float4*)&qls[t * 132 + hb + 4];
      float4 q2 = *(const float4*)&qls[t * 132 + hb + 8];
      float4 q3 = *(const float4*)&qls[t * 132 + hb + 12];
      float a[8];
#pragma unroll
      for (int j = 0; j < 8; ++j) {
        int s = sg + 8 * j;
        const float* kr = &kls[s * 132 + hb];
        float4 k0 = *(const float4*)&kr[0];
        float4 k1 = *(const float4*)&kr[4];
        float4 k2 = *(const float4*)&kr[8];
        float4 k3 = *(const float4*)&kr[12];
        a[j] = (q0.x * k0.x + q0.y * k0.y + q0.z * k0.z + q0.w * k0.w +
                q1.x * k1.x + q1.y * k1.y + q1.z * k1.z + q1.w * k1.w +
                q2.x * k2.x + q2.y * k2.y + q2.z * k2.z + q2.w * k2.w +
                q3.x * k3.x + q3.y * k3.y + q3.z * k3.z + q3.w * k3.w) * 0.25f;
      }
      float mx = a[0];
#pragma unroll
      for (int j = 1; j < 8; ++j) mx = fmaxf(mx, a[j]);
#pragma unroll
      for (int m = 4; m > 0; m >>= 1) mx = fmaxf(mx, __shfl_xor(mx, m, 8));
      float sum = 0.f;
#pragma unroll
      for (int j = 0; j < 8; ++j) { a[j] = __expf(a[j] - mx); sum += a[j]; }
#pragma unroll
      for (int m = 4; m > 0; m >>= 1) sum += __shfl_xor(sum, m, 8);
      float inv = 1.f / sum;
#pragma unroll
      for (int j = 0; j < 8; ++j) a[j] *= inv;
      float o[16];
#pragma unroll
      for (int d = 0; d < 16; ++d) o[d] = 0.f;
#pragma unroll
      for (int j = 0; j < 8; ++j) {
        int s = sg + 8 * j;
        const float* vr = &vls[s * 132 + hb];
        float w = a[j];
#pragma unroll
        for (int d = 0; d < 16; ++d) o[d] += w * vr[d];
      }
#pragma unroll
      for (int m = 4; m > 0; m >>= 1)
#pragma unroll
        for (int d = 0; d < 16; ++d) o[d] += __shfl_xor(o[d], m, 8);
      if (sg < 4) {
        float4 r4;
        r4.x = o[sg * 4 + 0]; r4.y = o[sg * 4 + 1];
        r4.z = o[sg * 4 + 2]; r4.w = o[sg * 4 + 3];
        *(float4*)&qls[t * 132 + hb + sg * 4] = r4;
      }
    }
  }
  __syncthreads();
  float* tr = vls;
  for (int idx = tid; idx < TILE; idx += 512) {
    int t = idx >> 7, c = idx & 127;
    tr[c * 66 + t] = qls[t * 132 + c];
  }
  __syncthreads();
  {
    int cg = tid & 31, tc = tid >> 5;
    int o0 = cg * 4, t0 = tc * 4;
    float4 bi = *(const float4*)&b2f[o0];
    float acc[4][4];
#pragma unroll
    for (int t = 0; t < 4; ++t) { acc[t][0] = bi.x; acc[t][1] = bi.y; acc[t][2] = bi.z; acc[t][3] = bi.w; }
    for (int i = 0; i < 128; ++i) {
      const float* xr = &tr[i * 66 + t0];
      float4 w4 = *(const float4*)&w2T[i * 128 + o0];
#pragma unroll
      for (int t = 0; t < 4; ++t) {
        float xv = xr[t];
        acc[t][0] += xv * w4.x; acc[t][1] += xv * w4.y; acc[t][2] += xv * w4.z; acc[t][3] += xv * w4.w;
      }
    }
#pragma unroll
    for (int t = 0; t < 4; ++t) {
      float4 r4; r4.x = acc[t][0]; r4.y = acc[t][1]; r4.z = acc[t][2]; r4.w = acc[t][3];
      *(float4*)&kls[(t0 + t) * 132 + o0] = r4;
    }
  }
  __syncthreads();
  {
    int r = tid >> 3, sg = tid & 7;
    float s = 0.f, q2 = 0.f;
    const float* row = &kls[r * 132 + sg * 16];
    for (int u = 0; u < 16; ++u) {
      float v = row[u];
      s += v; q2 += v * v;
    }
#pragma unroll
    for (int m = 4; m > 0; m >>= 1) {
      s += __shfl_xor(s, m, 8);
      q2 += __shfl_xor(q2, m, 8);
    }
    if (sg == 0) {
      float mm = s * (1.f / 128.f);
      mrow[r] = mm;
      vrow[r] = rsqrtf(q2 * (1.f / 128.f) - mm * mm + 1e-5f);
    }
  }
  __syncthreads();
  float* dst = g0 + (size_t)bn * TILE;
  for (int idx = tid; idx < TILE; idx += 512) {
    int t = idx >> 7, c = idx & 127;
    dst[idx] = (kls[t * 132 + c] - mrow[t]) * vrow[t] * l0g[c] + l0b[c] + xs[c * 68 + t + 1];
  }
}

// ================================================================ megasp v3 (unchanged from r7):
__global__ __launch_bounds__(512, 1) void k_megasp(
    const float* g0, const float* lap, float* yout) {
  int bt = blockIdx.x, b = bt >> 6, t = bt & 63;
  __shared__ float xts[256 * 132];
  __shared__ float scs[16 * 260];
  int tid = threadIdx.x;
  size_t base = (size_t)b * (N * (size_t)TILE) + (size_t)t * 128;
  for (int idx = tid * 4; idx < 32768; idx += 2048) {
    int n = idx >> 7, c = idx & 127;
    float4 v4 = *(const float4*)&g0[base + (size_t)n * TILE + c];
    *(float4*)&xts[n * 132 + c] = v4;
  }
  __syncthreads();
  const float sc = 0.08838834764831845f;
  int r = tid >> 5;
  int sg = tid & 31;
  int oc = sg * 4;
  float* yb = yout + (size_t)bt * 32768;
  for (int chunk = 0; chunk < 16; ++chunk) {
    int n0 = chunk * 16;
    int n = n0 + r;
    float a[8];
#pragma unroll
    for (int jj = 0; jj < 8; ++jj) a[jj] = 0.f;
    const float* qrow = &xts[n * 132];
    for (int k = 0; k < 128; k += 4) {
      float4 q4 = *(const float4*)&qrow[k];
#pragma unroll
      for (int jj = 0; jj < 8; ++jj) {
        const float4 m4 = *(const float4*)&xts[(sg + 32 * jj) * 132 + k];
        a[jj] += q4.x * m4.x + q4.y * m4.y + q4.z * m4.z + q4.w * m4.w;
      }
    }
    float mloc = -1e30f;
#pragma unroll
    for (int jj = 0; jj < 8; ++jj) { a[jj] *= sc; mloc = fmaxf(mloc, a[jj]); }
#pragma unroll
    for (int s = 16; s > 0; s >>= 1) mloc = fmaxf(mloc, __shfl_xor(mloc, s, 32));
    float ssum = 0.f;
#pragma unroll
    for (int jj = 0; jj < 8; ++jj) { a[jj] = __expf(a[jj] - mloc); ssum += a[jj]; }
#pragma unroll
    for (int s = 16; s > 0; s >>= 1) ssum += __shfl_xor(ssum, s, 32);
    float inv = sc / ssum;
    const float* lrow = &lap[n * 256];
#pragma unroll
    for (int jj = 0; jj < 8; ++jj) {
      int m = sg + 32 * jj;
      scs[r * 260 + m] = a[jj] * inv * lrow[m];
    }
    __syncthreads();
    {
      float4 acc = {0.f, 0.f, 0.f, 0.f};
      const float* srow = &scs[r * 260];
      for (int m2 = 0; m2 < 256; ++m2) {
        float w = srow[m2];
        float4 x4 = *(const float4*)&xts[m2 * 132 + oc];
        acc.x += w * x4.x; acc.y += w * x4.y; acc.z += w * x4.z; acc.w += w * x4.w;
      }
      *(float4*)&yb[(size_t)n * 128 + oc] = acc;
    }
    __syncthreads();
  }
}

// ================================================================ k_theta (unchanged from r7):
__global__ __launch_bounds__(512, 4) void k_theta(
    const float* y, const unsigned short* thB, float* g0,
    const float* l1g, const float* l1b, const float* e) {
  int bt = blockIdx.x, b = bt >> 6, t = bt & 63;
  __shared__ unsigned short ths[16384];
  __shared__ float ybuf[32 * 132];
  int tid = threadIdx.x;
  for (int idx = tid * 8; idx < 16384; idx += 4096)
    *(uint4*)&ths[idx] = *(const uint4*)&thB[idx];
  int r = tid >> 4;
  int sg = tid & 15;
  int oc = sg * 8;
  const float* eb = e + b * 128;
  float gg[8], bb[8], ev[8];
#pragma unroll
  for (int u = 0; u < 8; ++u) { gg[u] = l1g[oc + u]; bb[u] = l1b[oc + u]; ev[u] = eb[oc + u]; }
  const float* ybase = y + (size_t)bt * 32768;
  __syncthreads();
  for (int chunk = 0; chunk < 8; ++chunk) {
    int n0 = chunk * 32;
    for (int idx = tid * 4; idx < 4096; idx += 2048) {
      int rr = idx >> 7, c = idx & 127;
      *(float4*)&ybuf[rr * 132 + c] = *(const float4*)&ybase[(size_t)(n0 + rr) * 128 + c];
    }
    __syncthreads();
    float acc[8];
#pragma unroll
    for (int u = 0; u < 8; ++u) acc[u] = 0.f;
    const float* yrow = &ybuf[r * 132];
    for (int i = 0; i < 128; ++i) {
      float yv = yrow[i];
      uint4 w = *(const uint4*)&ths[i * 128 + oc];
      float w0 = __uint_as_float(w.x << 16);
      float w1 = __uint_as_float(w.x & 0xffff0000u);
      float w2 = __uint_as_float(w.y << 16);
      float w3 = __uint_as_float(w.y & 0xffff0000u);
      float w4 = __uint_as_float(w.z << 16);
      float w5 = __uint_as_float(w.z & 0xffff0000u);
      float w6 = __uint_as_float(w.w << 16);
      float w7 = __uint_as_float(w.w & 0xffff0000u);
      acc[0] += yv * w0; acc[1] += yv * w1; acc[2] += yv * w2; acc[3] += yv * w3;
      acc[4] += yv * w4; acc[5] += yv * w5; acc[6] += yv * w6; acc[7] += yv * w7;
    }
    float sps = 0.f, spq = 0.f;
#pragma unroll
    for (int u = 0; u < 8; ++u) {
      acc[u] = fmaxf(acc[u], 0.f);
      sps += acc[u]; spq += acc[u] * acc[u];
    }
#pragma unroll
    for (int m = 8; m > 0; m >>= 1) {
      sps += __shfl_xor(sps, m, 16);
      spq += __shfl_xor(spq, m, 16);
    }
    float mm = sps * (1.f / 128.f);
    float rs = rsqrtf(spq * (1.f / 128.f) - mm * mm + 1e-5f);
    int n = n0 + r;
    size_t ga = ((size_t)(b * 256 + n)) * TILE + (size_t)t * 128 + oc;
    float4 xa = *(const float4*)&g0[ga];
    float4 xb4 = *(const float4*)&g0[ga + 4];
    float4 h0, h1;
    h0.x = (acc[0] - mm) * rs * gg[0] + bb[0] + xa.x + ev[0];
    h0.y = (acc[1] - mm) * rs * gg[1] + bb[1] + xa.y + ev[1];
    h0.z = (acc[2] - mm) * rs * gg[2] + bb[2] + xa.z + ev[2];
    h0.w = (acc[3] - mm) * rs * gg[3] + bb[3] + xa.w + ev[3];
    h1.x = (acc[4] - mm) * rs * gg[4] + bb[4] + xb4.x + ev[4];
    h1.y = (acc[5] - mm) * rs * gg[5] + bb[5] + xb4.y + ev[5];
    h1.z = (acc[6] - mm) * rs * gg[6] + bb[6] + xb4.z + ev[6];
    h1.w = (acc[7] - mm) * rs * gg[7] + bb[7] + xb4.w + ev[7];
    *(float4*)&g0[ga] = h0;
    *(float4*)&g0[ga + 4] = h1;
    __syncthreads();
  }
}

// ================================================================ megadec v3 — MFMA.
// per (b,n): im2col(h) bf16 in LDS; three 128x64xK384 convs on matrix cores.
// A = W[o][k] (global bf16, lane m=lane&15, k contiguous); B = [t][k] LDS
// (lane n=lane&15); D: col=lane&15 (t), row=quad*4+reg (o).
constexpr int SB = 392;  // bf16 per im2col row (384 + 8 pad)

__global__ __launch_bounds__(512, 1) void k_megadec(
    const float* g0, const unsigned short* decW, const float* decb,
    const unsigned short* dxcW, const float* dxcb,
    const unsigned short* dc1W, const float* dc1b,
    const float* dp2w, const float* dp2b, const int* flag, void* outv) {
  int bn = blockIdx.x, b = bn >> 8, n = bn & 255;
  int f32o = flag[0];
  __shared__ unsigned short Bm[64 * SB];   // im2col(h)  50.2 KB
  __shared__ unsigned short B2[64 * SB];   // im2col(ec) 50.2 KB
  __shared__ float pb0[8][64], pb1[8][64]; // proj partials 4 KB
  int tid = threadIdx.x;
  int wv = tid >> 6, lane = tid & 63, quad = lane >> 4, lr = lane & 15;
  int m0 = wv * 16;
  // ---- stage im2col(h) as bf16: Bm[t2][j*128+c] = h[t2+j-1][c]
  const float* gp = g0 + (size_t)bn * TILE;
  for (int idx = tid * 4; idx < TILE; idx += 2048) {
    int t = idx >> 7, c = idx & 127;
    float4 v4 = *(const float4*)&gp[idx];
    ushort4 pk;
    pk.x = f2b(v4.x); pk.y = f2b(v4.y); pk.z = f2b(v4.z); pk.w = f2b(v4.w);
    *(ushort4*)&Bm[t * SB + 128 + c] = pk;                    // j=1
    if (t < 63) *(ushort4*)&Bm[(t + 1) * SB + c] = pk;        // j=0
    if (t > 0)  *(ushort4*)&Bm[(t - 1) * SB + 256 + c] = pk;  // j=2
  }
  if (tid < 128) {  // zero pads (h[-1], h[64]) for both matrices
    Bm[0 * SB + tid] = 0;  Bm[63 * SB + 256 + tid] = 0;
    B2[0 * SB + tid] = 0;  B2[63 * SB + 256 + tid] = 0;
  }
  __syncthreads();
  // ---- conv dec -> ec (regs) + scatter im2col(ec) into B2
  v4f acc[4];
  float ecv[4][4];
#pragma unroll
  for (int nt = 0; nt < 4; ++nt) acc[nt] = (v4f){0.f, 0.f, 0.f, 0.f};
  for (int kt = 0; kt < 12; ++kt) {
    v8s a = *(const v8s*)&decW[(m0 + lr) * 384 + kt * 32 + quad * 8];
#pragma unroll
    for (int nt = 0; nt < 4; ++nt) {
      v8s bb = *(const v8s*)&Bm[(nt * 16 + lr) * SB + kt * 32 + quad * 8];
      acc[nt] = __builtin_amdgcn_mfma_f32_16x16x32_bf16(a, bb, acc[nt], 0, 0, 0);
    }
  }
#pragma unroll
  for (int nt = 0; nt < 4; ++nt) {
    int t = nt * 16 + lr;
#pragma unroll
    for (int r = 0; r < 4; ++r) {
      int o = m0 + quad * 4 + r;
      float v = acc[nt][r] + decb[o];
      ecv[nt][r] = v;
      unsigned short bv = f2b(v);
      B2[t * SB + 128 + o] = bv;                    // j=1
      if (t < 63) B2[(t + 1) * SB + o] = bv;        // j=0
      if (t > 0)  B2[(t - 1) * SB + 256 + o] = bv;  // j=2
    }
  }
  __syncthreads();
  // ---- conv dxc (on Bm) and conv dc1 (on B2), fused gate + relu + projection
  v4f ax[4], ac[4];
#pragma unroll
  for (int nt = 0; nt < 4; ++nt) { ax[nt] = (v4f){0.f,0.f,0.f,0.f}; ac[nt] = (v4f){0.f,0.f,0.f,0.f}; }
  for (int kt = 0; kt < 12; ++kt) {
    v8s a1 = *(const v8s*)&dxcW[(m0 + lr) * 384 + kt * 32 + quad * 8];
    v8s a2 = *(const v8s*)&dc1W[(m0 + lr) * 384 + kt * 32 + quad * 8];
#pragma unroll
    for (int nt = 0; nt < 4; ++nt) {
      v8s b1 = *(const v8s*)&Bm[(nt * 16 + lr) * SB + kt * 32 + quad * 8];
      v8s b2v = *(const v8s*)&B2[(nt * 16 + lr) * SB + kt * 32 + quad * 8];
      ax[nt] = __builtin_amdgcn_mfma_f32_16x16x32_bf16(a1, b1, ax[nt], 0, 0, 0);
      ac[nt] = __builtin_amdgcn_mfma_f32_16x16x32_bf16(a2, b2v, ac[nt], 0, 0, 0);
    }
  }
#pragma unroll
  for (int nt = 0; nt < 4; ++nt) {
    float p0 = 0.f, p1 = 0.f;
#pragma unroll
    for (int r = 0; r < 4; ++r) {
      int o = m0 + quad * 4 + r;
      float v = fmaxf(ax[nt][r] + dxcb[o] + sigm(ecv[nt][r]) + ac[nt][r] + dc1b[o], 0.f);
      p0 += v * dp2w[o];
      p1 += v * dp2w[128 + o];
    }
    p0 += __shfl_xor(p0, 16, 64); p0 += __shfl_xor(p0, 32, 64);
    p1 += __shfl_xor(p1, 16, 64); p1 += __shfl_xor(p1, 32, 64);
    if (quad == 0) { pb0[wv][nt * 16 + lr] = p0; pb1[wv][nt * 16 + lr] = p1; }
  }
  __syncthreads();
  if (tid < 128) {
    int ch = tid >> 6, t = tid & 63;
    float s = 0.f;
    if (ch == 0) { for (int w = 0; w < 8; ++w) s += pb0[w][t]; s += dp2b[0]; }
    else         { for (int w = 0; w < 8; ++w) s += pb1[w][t]; s += dp2b[1]; }
    size_t oi = ((size_t)(b * 2 + ch) * 256 + n) * 64 + t;
    if (f32o) ((float*)outv)[oi] = s;
    else ((__hip_bfloat16*)outv)[oi] = __float2bfloat16(s);
  }
}

}  // namespace

extern "C" void kernel_launch(void* const* d_in, const int* in_sizes, int n_in,
                              void* d_out, int out_size, void* d_ws, size_t ws_size,
                              hipStream_t stream) {
  (void)in_sizes; (void)n_in; (void)out_size; (void)ws_size;
  const void* x    = d_in[0];
  const void* adj  = d_in[1];
  const int*  step = (const int*)d_in[2];
  const void* wq   = d_in[3];
  const void* bq   = d_in[4];
  const void* wk   = d_in[5];
  const void* bk   = d_in[6];
  const void* w1   = d_in[7];
  const void* b1   = d_in[8];
  const void* w2   = d_in[9];
  const void* b2   = d_in[10];
  const void* th   = d_in[11];
  const void* l0g  = d_in[12];
  const void* l0b  = d_in[13];
  const void* l1g  = d_in[14];
  const void* l1b  = d_in[15];
  const void* p1w  = d_in[16];
  const void* p1b  = d_in[17];
  const void* p2w  = d_in[18];
  const void* p2b  = d_in[19];
  const void* dxcw = d_in[20];
  const void* dxcb = d_in[21];
  const void* decw = d_in[22];
  const void* decb = d_in[23];
  const void* dc1w = d_in[24];
  const void* dc1b = d_in[25];
  const void* dp2w = d_in[26];
  const void* dp2b = d_in[27];

  float* ws = (float*)d_ws;
  int* flag = (int*)ws;
  float* p = ws + 16;
  float* e     = p; p += 1024;
  float* lap   = p; p += 65536;
  float* wqkT  = p; p += 98304;
  float* w1T   = p; p += 16384;
  float* w2T   = p; p += 16384;
  float* thT   = p; p += 16384;
  float* thBv  = p; p += 8192;    // 16384 bf16
  float* decWv = p; p += 24576;   // 49152 bf16
  float* dxcWv = p; p += 24576;
  float* dc1Wv = p; p += 24576;
  float* bqk   = p; p += 256;
  float* b1f   = p; p += 128;
  float* b2f   = p; p += 128;
  float* l0gf  = p; p += 128;
  float* l0bf  = p; p += 128;
  float* l1gf  = p; p += 128;
  float* l1bf  = p; p += 128;
  float* dxcbf = p; p += 128;
  float* decbf = p; p += 128;
  float* dc1bf = p; p += 128;
  float* dp2wf = p; p += 256;
  float* dp2bf = p; p += 8;
  size_t off = (size_t)(p - ws);
  off = (off + 127) & ~(size_t)127;
  float* xf = ws + off;            // BIGE floats (67 MB); y overwrites after mega1
  float* g0 = xf + BIGE;           // BIGE floats (67 MB)

  PrepArgs pa;
  pa.flag = flag;
  pa.wq = wq; pa.wk = wk; pa.w1 = w1; pa.w2 = w2; pa.th = th;
  pa.dxc = dxcw; pa.dec = decw; pa.dc1 = dc1w;
  pa.bq = bq; pa.bk = bk; pa.b1 = b1; pa.b2 = b2;
  pa.l0g = l0g; pa.l0b = l0b; pa.l1g = l1g; pa.l1b = l1b;
  pa.dxcb = dxcb; pa.decb = decb; pa.dc1b = dc1b; pa.dp2w = dp2w; pa.dp2b = dp2b;
  pa.wqkT = wqkT; pa.w1T = w1T; pa.w2T = w2T; pa.thT = thT;
  pa.thB = (__hip_bfloat16*)thBv;
  pa.decWb = (unsigned short*)decWv;
  pa.dxcWb = (unsigned short*)dxcWv;
  pa.dc1Wb = (unsigned short*)dc1Wv;
  pa.bqk = bqk; pa.b1f = b1f; pa.b2f = b2f;
  pa.l0gf = l0gf; pa.l0bf = l0bf; pa.l1gf = l1gf; pa.l1bf = l1bf;
  pa.dxcbf = dxcbf; pa.decbf = decbf; pa.dc1bf = dc1bf; pa.dp2wf = dp2wf; pa.dp2bf = dp2bf;

  k_sniff<<<1, 64, 0, stream>>>((const unsigned short*)x, flag);
  k_cvtx<<<1024, 256, 0, stream>>>(x, flag, xf);
  k_prep<<<128, 256, 0, stream>>>(pa);
  k_lap<<<1, 256, 0, stream>>>(adj, flag, lap);
  k_emb<<<8, 128, 0, stream>>>(step, flag, p1w, p1b, p2w, p2b, e);

  k_mega1<<<2048, 512, 0, stream>>>(xf, wqkT, bqk, w1T, b1f, w2T, b2f, l0gf, l0bf, g0);
  k_megasp<<<512, 512, 0, stream>>>(g0, lap, xf);               // y -> xf (x dead)
  k_theta<<<512, 512, 0, stream>>>(xf, (const unsigned short*)thBv, g0, l1gf, l1bf, e);
  k_megadec<<<2048, 512, 0, stream>>>(g0, (const unsigned short*)decWv, decbf,
                                      (const unsigned short*)dxcWv, dxcbf,
                                      (const unsigned short*)dc1Wv, dc1bf,
                                      dp2wf, dp2bf, flag, d_out);
}

// Round 9
// 1147.879 us; speedup vs baseline: 2.0810x; 1.3233x over previous
//
#include <hip/hip_runtime.h>
#include <hip/hip_bf16.h>

namespace {

constexpr int C = 128, N = 256, T = 64, Bsz = 8;
constexpr int TILE = T * C;                       // 8192 elements per (b,n) slab
constexpr size_t BIGE = (size_t)Bsz * N * T * C;  // 16,777,216 elements

typedef short v8s __attribute__((ext_vector_type(8)));
typedef float v4f __attribute__((ext_vector_type(4)));

__device__ __forceinline__ float bfu(unsigned short u) {
  unsigned int x = ((unsigned int)u) << 16;
  return __uint_as_float(x);
}
__device__ __forceinline__ unsigned short f2b(float v) {
  __hip_bfloat16 h = __float2bfloat16(v);
  return *(unsigned short*)&h;
}
// flag-aware load: f32 != 0 -> input is fp32, else bf16
__device__ __forceinline__ float ld(const void* p, size_t i, int f32) {
  if (f32) return ((const float*)p)[i];
  return bfu(((const unsigned short*)p)[i]);
}
__device__ __forceinline__ float sigm(float x) { return 1.f / (1.f + __expf(-x)); }

// ---------------------------------------------------------------- dtype sniffer
__global__ __launch_bounds__(64) void k_sniff(const unsigned short* x, int* flag) {
  __shared__ int cnt[64];
  int tid = threadIdx.x;
  int c = 0;
  for (int u = 0; u < 8; ++u) {
    unsigned short v = x[tid * 8 + u];
    int e = (v >> 7) & 255;
    c += (e >= 97 && e <= 157) ? 1 : 0;
  }
  cnt[tid] = c;
  __syncthreads();
  if (tid == 0) {
    int s = 0;
    for (int i = 0; i < 64; ++i) s += cnt[i];
    flag[0] = (s < 435) ? 1 : 0;  // <85% plausible-bf16 words -> fp32 input
  }
}

// ---------------------------------------------------------------- prep (all mat weights -> bf16 MFMA layouts)
struct PrepArgs {
  const int* flag;
  const void *wq, *wk, *w1, *w2, *th, *dxc, *dec, *dc1;
  const void *bq, *bk, *b1, *b2, *l0g, *l0b, *l1g, *l1b, *dxcb, *decb, *dc1b, *dp2w, *dp2b;
  unsigned short *wqkB, *w1B, *w2B;        // bf16 [o][k]
  __hip_bfloat16* thB;                     // bf16 [k][o]
  unsigned short *decWb, *dxcWb, *dc1Wb;   // bf16 [o][k], k = j*128+i
  float *bqk, *b1f, *b2f, *l0gf, *l0bf, *l1gf, *l1bf, *dxcbf, *decbf, *dc1bf, *dp2wf, *dp2bf;
};

__global__ __launch_bounds__(256) void k_prep(PrepArgs a) {
  int f = a.flag[0];
  int idx = blockIdx.x * blockDim.x + threadIdx.x;
  int stride = gridDim.x * blockDim.x;
  // wqkB[o][k=j*128+ii], o<128 -> wq else wk. src w[(o*128+ii)*3 + j]
  for (int i = idx; i < 256 * 384; i += stride) {
    int o = i / 384, k = i - o * 384;
    int j = k >> 7, ii = k & 127;
    float v = (o < 128) ? ld(a.wq, (o * 128 + ii) * 3 + j, f)
                        : ld(a.wk, ((o - 128) * 128 + ii) * 3 + j, f);
    a.wqkB[i] = f2b(v);
  }
  for (int i = idx; i < 16384; i += stride) {
    a.w1B[i] = f2b(ld(a.w1, i, f));   // already [o][k] row-major
    a.w2B[i] = f2b(ld(a.w2, i, f));
    int k = i >> 7, o = i & 127;
    a.thB[i] = __float2bfloat16(ld(a.th, o * 128 + k, f));  // [k][o]
  }
  // decoder conv weights -> bf16 [o][k = j*128 + ii]
  for (int i = idx; i < 16384; i += stride) {
    int o = i >> 7, ii = i & 127;
    int sbase = (o * 128 + ii) * 3;
#pragma unroll
    for (int j = 0; j < 3; ++j) {
      int dsti = o * 384 + j * 128 + ii;
      a.decWb[dsti] = f2b(ld(a.dec, sbase + j, f));
      a.dxcWb[dsti] = f2b(ld(a.dxc, sbase + j, f));
      a.dc1Wb[dsti] = f2b(ld(a.dc1, sbase + j, f));
    }
  }
  for (int i = idx; i < 256; i += stride) {
    a.bqk[i] = (i < 128) ? ld(a.bq, i, f) : ld(a.bk, i - 128, f);
    a.dp2wf[i] = ld(a.dp2w, i, f);
  }
  for (int i = idx; i < 128; i += stride) {
    a.b1f[i] = ld(a.b1, i, f);   a.b2f[i] = ld(a.b2, i, f);
    a.l0gf[i] = ld(a.l0g, i, f); a.l0bf[i] = ld(a.l0b, i, f);
    a.l1gf[i] = ld(a.l1g, i, f); a.l1bf[i] = ld(a.l1b, i, f);
    a.dxcbf[i] = ld(a.dxcb, i, f); a.decbf[i] = ld(a.decb, i, f); a.dc1bf[i] = ld(a.dc1b, i, f);
  }
  if (idx < 2) a.dp2bf[idx] = ld(a.dp2b, idx, f);
}

__global__ __launch_bounds__(256) void k_lap(const void* adj, const int* flag, float* lap) {
  __shared__ float dsh[256];
  int f = flag[0];
  int tid = threadIdx.x;
  float s = 0.f;
  for (int m = 0; m < 256; ++m) s += ld(adj, tid * 256 + m, f);
  dsh[tid] = 1.f / sqrtf(s);
  __syncthreads();
  for (int idx = tid; idx < 65536; idx += 256) {
    int n = idx >> 8, m = idx & 255;
    lap[idx] = ld(adj, idx, f) * dsh[n] * dsh[m];
  }
}

__global__ __launch_bounds__(128) void k_emb(const int* step, const int* flag,
                                             const void* p1w, const void* p1b,
                                             const void* p2w, const void* p2b, float* e) {
  int b = blockIdx.x, c = threadIdx.x;
  int f = flag[0];
  __shared__ float tab[128], e1[128];
  float sv = (float)step[b];
  int i0 = c & 63;
  float fr = powf(10.f, (float)i0 / 63.f * 4.f);
  float ang = sv * fr;
  tab[c] = (c < 64) ? sinf(ang) : cosf(ang);
  __syncthreads();
  float a = ld(p1b, c, f);
  for (int i = 0; i < 128; ++i) a += tab[i] * ld(p1w, c * 128 + i, f);
  a = a * sigm(a);
  e1[c] = a;
  __syncthreads();
  float a2 = ld(p2b, c, f);
  for (int i = 0; i < 128; ++i) a2 += e1[i] * ld(p2w, c * 128 + i, f);
  e[b * 128 + c] = a2 * sigm(a2);
}

constexpr int SB = 392;   // bf16 per im2col row (384 + 8 pad)
constexpr int SO = 136;   // bf16 per o-row (128 + 8 pad)

// ================================================================ mega1 v5 — MFMA GEMMs.
// per (b,n): im2col(x) bf16 in LDS; QK conv (M=256,K=384), V (M=128,K=128) on
// matrix cores -> q/k/v fp32 LDS; VALU attention (r5-proven); o->bf16 -> w2
// MFMA; LN0 + residual(x from im2col j=1) -> xp (fp32) to g0.
__global__ __launch_bounds__(512, 1) void k_mega1(
    const void* xin, const int* flag,
    const unsigned short* wqkB, const float* bqk,
    const unsigned short* w1B, const float* b1f,
    const unsigned short* w2B, const float* b2f,
    const float* l0g, const float* l0b, float* g0) {
  int bn = blockIdx.x, b = bn >> 8, n = bn & 255;
  __shared__ unsigned short Bx[64 * SB];   // im2col(x) bf16, 50.2 KB
  __shared__ float qls[64 * 132];          // q; later o
  __shared__ float kls[64 * 132];          // k; later o.w2^T
  __shared__ float vls[64 * 132];          // v; later Bo (bf16 o) alias
  __shared__ float mrow[64], vrow[64];
  int tid = threadIdx.x;
  int wv = tid >> 6, lane = tid & 63, quad = lane >> 4, lr = lane & 15;
  int f = flag[0];
  // ---- stage im2col(x): Bx[t2][j*128+c] = x[c][t2+j-1]
  {
    size_t xoff = (size_t)b * C * N * T + (size_t)n * T;
    for (int idx = tid * 4; idx < TILE; idx += 2048) {
      int i = idx >> 6, t = idx & 63;   // t multiple of 4
      unsigned short pk[4];
      if (f) {
        float4 v4 = *(const float4*)&((const float*)xin)[xoff + (size_t)i * N * T + t];
        pk[0] = f2b(v4.x); pk[1] = f2b(v4.y); pk[2] = f2b(v4.z); pk[3] = f2b(v4.w);
      } else {
        ushort4 u4 = *(const ushort4*)&((const unsigned short*)xin)[xoff + (size_t)i * N * T + t];
        pk[0] = u4.x; pk[1] = u4.y; pk[2] = u4.z; pk[3] = u4.w;
      }
#pragma unroll
      for (int u = 0; u < 4; ++u) {
        int t2 = t + u;
        Bx[t2 * SB + 128 + i] = pk[u];                    // j=1
        if (t2 < 63) Bx[(t2 + 1) * SB + i] = pk[u];       // j=0
        if (t2 > 0)  Bx[(t2 - 1) * SB + 256 + i] = pk[u]; // j=2
      }
    }
  }
  if (tid < 128) { Bx[0 * SB + tid] = 0; Bx[63 * SB + 256 + tid] = 0; }
  __syncthreads();
  // ---- QK conv MFMA: wave wv handles m-tiles {2wv, 2wv+1}; o = 32wv..32wv+31
  {
    int mt0 = wv * 2;
    v4f acc[2][4];
#pragma unroll
    for (int mi = 0; mi < 2; ++mi)
#pragma unroll
      for (int nt = 0; nt < 4; ++nt) acc[mi][nt] = (v4f){0.f, 0.f, 0.f, 0.f};
    for (int kt = 0; kt < 12; ++kt) {
      v8s a0 = *(const v8s*)&wqkB[(mt0 * 16 + lr) * 384 + kt * 32 + quad * 8];
      v8s a1 = *(const v8s*)&wqkB[((mt0 + 1) * 16 + lr) * 384 + kt * 32 + quad * 8];
#pragma unroll
      for (int nt = 0; nt < 4; ++nt) {
        v8s bb = *(const v8s*)&Bx[(nt * 16 + lr) * SB + kt * 32 + quad * 8];
        acc[0][nt] = __builtin_amdgcn_mfma_f32_16x16x32_bf16(a0, bb, acc[0][nt], 0, 0, 0);
        acc[1][nt] = __builtin_amdgcn_mfma_f32_16x16x32_bf16(a1, bb, acc[1][nt], 0, 0, 0);
      }
    }
    float* dst = (wv < 4) ? qls : kls;
#pragma unroll
    for (int mi = 0; mi < 2; ++mi) {
      int ob = (mt0 + mi) * 16 + quad * 4;
      int oo = ob & 127;
#pragma unroll
      for (int nt = 0; nt < 4; ++nt) {
        int t = nt * 16 + lr;
#pragma unroll
        for (int r = 0; r < 4; ++r)
          dst[t * 132 + oo + r] = acc[mi][nt][r] + bqk[ob + r];
      }
    }
  }
  // ---- V MFMA: wave wv handles o = 16wv..16wv+15, K=128 (j=1 slice of Bx)
  {
    v4f av[4];
#pragma unroll
    for (int nt = 0; nt < 4; ++nt) av[nt] = (v4f){0.f, 0.f, 0.f, 0.f};
    for (int kt = 0; kt < 4; ++kt) {
      v8s a = *(const v8s*)&w1B[(wv * 16 + lr) * 128 + kt * 32 + quad * 8];
#pragma unroll
      for (int nt = 0; nt < 4; ++nt) {
        v8s bb = *(const v8s*)&Bx[(nt * 16 + lr) * SB + 128 + kt * 32 + quad * 8];
        av[nt] = __builtin_amdgcn_mfma_f32_16x16x32_bf16(a, bb, av[nt], 0, 0, 0);
      }
    }
    int ob = wv * 16 + quad * 4;
#pragma unroll
    for (int nt = 0; nt < 4; ++nt) {
      int t = nt * 16 + lr;
#pragma unroll
      for (int r = 0; r < 4; ++r)
        vls[t * 132 + ob + r] = av[nt][r] + b1f[ob + r];
    }
  }
  __syncthreads();
  // ---- temporal attention (r5-proven): 8-lane group per q-row; heads sequential
  {
    int t = tid >> 3;
    int sg = tid & 7;
    for (int h = 0; h < 8; ++h) {
      int hb = h * 16;
      float4 q0 = *(const float4*)&qls[t * 132 + hb];
      float4 q1 = *(const float4*)&qls[t * 132 + hb + 4];
      float4 q2 = *(const float4*)&qls[t * 132 + hb + 8];
      float4 q3 = *(const float4*)&qls[t * 132 + hb + 12];
      float a[8];
#pragma unroll
      for (int j = 0; j < 8; ++j) {
        int s = sg + 8 * j;
        const float* kr = &kls[s * 132 + hb];
        float4 k0 = *(const float4*)&kr[0];
        float4 k1 = *(const float4*)&kr[4];
        float4 k2 = *(const float4*)&kr[8];
        float4 k3 = *(const float4*)&kr[12];
        a[j] = (q0.x * k0.x + q0.y * k0.y + q0.z * k0.z + q0.w * k0.w +
                q1.x * k1.x + q1.y * k1.y + q1.z * k1.z + q1.w * k1.w +
                q2.x * k2.x + q2.y * k2.y + q2.z * k2.z + q2.w * k2.w +
                q3.x * k3.x + q3.y * k3.y + q3.z * k3.z + q3.w * k3.w) * 0.25f;
      }
      float mx = a[0];
#pragma unroll
      for (int j = 1; j < 8; ++j) mx = fmaxf(mx, a[j]);
#pragma unroll
      for (int m = 4; m > 0; m >>= 1) mx = fmaxf(mx, __shfl_xor(mx, m, 8));
      float sum = 0.f;
#pragma unroll
      for (int j = 0; j < 8; ++j) { a[j] = __expf(a[j] - mx); sum += a[j]; }
#pragma unroll
      for (int m = 4; m > 0; m >>= 1) sum += __shfl_xor(sum, m, 8);
      float inv = 1.f / sum;
#pragma unroll
      for (int j = 0; j < 8; ++j) a[j] *= inv;
      float o[16];
#pragma unroll
      for (int d = 0; d < 16; ++d) o[d] = 0.f;
#pragma unroll
      for (int j = 0; j < 8; ++j) {
        int s = sg + 8 * j;
        const float* vr = &vls[s * 132 + hb];
        float w = a[j];
#pragma unroll
        for (int d = 0; d < 16; ++d) o[d] += w * vr[d];
      }
#pragma unroll
      for (int m = 4; m > 0; m >>= 1)
#pragma unroll
        for (int d = 0; d < 16; ++d) o[d] += __shfl_xor(o[d], m, 8);
      if (sg < 4) {
        float4 r4;
        r4.x = o[sg * 4 + 0]; r4.y = o[sg * 4 + 1];
        r4.z = o[sg * 4 + 2]; r4.w = o[sg * 4 + 3];
        *(float4*)&qls[t * 132 + hb + sg * 4] = r4;
      }
    }
  }
  __syncthreads();
  // ---- o -> bf16 Bo (alias vls)
  unsigned short* Bo = (unsigned short*)vls;
  for (int idx = tid; idx < TILE; idx += 512) {
    int t = idx >> 7, c = idx & 127;
    Bo[t * SO + c] = f2b(qls[t * 132 + c]);
  }
  __syncthreads();
  // ---- w2 MFMA: wave wv -> o = 16wv..16wv+15
  {
    v4f aw[4];
#pragma unroll
    for (int nt = 0; nt < 4; ++nt) aw[nt] = (v4f){0.f, 0.f, 0.f, 0.f};
    for (int kt = 0; kt < 4; ++kt) {
      v8s a = *(const v8s*)&w2B[(wv * 16 + lr) * 128 + kt * 32 + quad * 8];
#pragma unroll
      for (int nt = 0; nt < 4; ++nt) {
        v8s bb = *(const v8s*)&Bo[(nt * 16 + lr) * SO + kt * 32 + quad * 8];
        aw[nt] = __builtin_amdgcn_mfma_f32_16x16x32_bf16(a, bb, aw[nt], 0, 0, 0);
      }
    }
    int ob = wv * 16 + quad * 4;
#pragma unroll
    for (int nt = 0; nt < 4; ++nt) {
      int t = nt * 16 + lr;
#pragma unroll
      for (int r = 0; r < 4; ++r)
        kls[t * 132 + ob + r] = aw[nt][r] + b2f[ob + r];
    }
  }
  __syncthreads();
  // ---- LN0 stats via shuffles: 8-lane group per row
  {
    int r = tid >> 3, sg = tid & 7;
    float s = 0.f, q2 = 0.f;
    const float* row = &kls[r * 132 + sg * 16];
    for (int u = 0; u < 16; ++u) {
      float v = row[u];
      s += v; q2 += v * v;
    }
#pragma unroll
    for (int m = 4; m > 0; m >>= 1) {
      s += __shfl_xor(s, m, 8);
      q2 += __shfl_xor(q2, m, 8);
    }
    if (sg == 0) {
      float mm = s * (1.f / 128.f);
      mrow[r] = mm;
      vrow[r] = rsqrtf(q2 * (1.f / 128.f) - mm * mm + 1e-5f);
    }
  }
  __syncthreads();
  float* dst = g0 + (size_t)bn * TILE;
  for (int idx = tid; idx < TILE; idx += 512) {
    int t = idx >> 7, c = idx & 127;
    dst[idx] = (kls[t * 132 + c] - mrow[t]) * vrow[t] * l0g[c] + l0b[c]
               + bfu(Bx[t * SB + 128 + c]);
  }
}

// ================================================================ megasp v3 (unchanged):
__global__ __launch_bounds__(512, 1) void k_megasp(
    const float* g0, const float* lap, float* yout) {
  int bt = blockIdx.x, b = bt >> 6, t = bt & 63;
  __shared__ float xts[256 * 132];
  __shared__ float scs[16 * 260];
  int tid = threadIdx.x;
  size_t base = (size_t)b * (N * (size_t)TILE) + (size_t)t * 128;
  for (int idx = tid * 4; idx < 32768; idx += 2048) {
    int n = idx >> 7, c = idx & 127;
    float4 v4 = *(const float4*)&g0[base + (size_t)n * TILE + c];
    *(float4*)&xts[n * 132 + c] = v4;
  }
  __syncthreads();
  const float sc = 0.08838834764831845f;
  int r = tid >> 5;
  int sg = tid & 31;
  int oc = sg * 4;
  float* yb = yout + (size_t)bt * 32768;
  for (int chunk = 0; chunk < 16; ++chunk) {
    int n0 = chunk * 16;
    int n = n0 + r;
    float a[8];
#pragma unroll
    for (int jj = 0; jj < 8; ++jj) a[jj] = 0.f;
    const float* qrow = &xts[n * 132];
    for (int k = 0; k < 128; k += 4) {
      float4 q4 = *(const float4*)&qrow[k];
#pragma unroll
      for (int jj = 0; jj < 8; ++jj) {
        const float4 m4 = *(const float4*)&xts[(sg + 32 * jj) * 132 + k];
        a[jj] += q4.x * m4.x + q4.y * m4.y + q4.z * m4.z + q4.w * m4.w;
      }
    }
    float mloc = -1e30f;
#pragma unroll
    for (int jj = 0; jj < 8; ++jj) { a[jj] *= sc; mloc = fmaxf(mloc, a[jj]); }
#pragma unroll
    for (int s = 16; s > 0; s >>= 1) mloc = fmaxf(mloc, __shfl_xor(mloc, s, 32));
    float ssum = 0.f;
#pragma unroll
    for (int jj = 0; jj < 8; ++jj) { a[jj] = __expf(a[jj] - mloc); ssum += a[jj]; }
#pragma unroll
    for (int s = 16; s > 0; s >>= 1) ssum += __shfl_xor(ssum, s, 32);
    float inv = sc / ssum;
    const float* lrow = &lap[n * 256];
#pragma unroll
    for (int jj = 0; jj < 8; ++jj) {
      int m = sg + 32 * jj;
      scs[r * 260 + m] = a[jj] * inv * lrow[m];
    }
    __syncthreads();
    {
      float4 acc = {0.f, 0.f, 0.f, 0.f};
      const float* srow = &scs[r * 260];
      for (int m2 = 0; m2 < 256; ++m2) {
        float w = srow[m2];
        float4 x4 = *(const float4*)&xts[m2 * 132 + oc];
        acc.x += w * x4.x; acc.y += w * x4.y; acc.z += w * x4.z; acc.w += w * x4.w;
      }
      *(float4*)&yb[(size_t)n * 128 + oc] = acc;
    }
    __syncthreads();
  }
}

// ================================================================ k_theta (unchanged):
__global__ __launch_bounds__(512, 4) void k_theta(
    const float* y, const unsigned short* thB, float* g0,
    const float* l1g, const float* l1b, const float* e) {
  int bt = blockIdx.x, b = bt >> 6, t = bt & 63;
  __shared__ unsigned short ths[16384];
  __shared__ float ybuf[32 * 132];
  int tid = threadIdx.x;
  for (int idx = tid * 8; idx < 16384; idx += 4096)
    *(uint4*)&ths[idx] = *(const uint4*)&thB[idx];
  int r = tid >> 4;
  int sg = tid & 15;
  int oc = sg * 8;
  const float* eb = e + b * 128;
  float gg[8], bb[8], ev[8];
#pragma unroll
  for (int u = 0; u < 8; ++u) { gg[u] = l1g[oc + u]; bb[u] = l1b[oc + u]; ev[u] = eb[oc + u]; }
  const float* ybase = y + (size_t)bt * 32768;
  __syncthreads();
  for (int chunk = 0; chunk < 8; ++chunk) {
    int n0 = chunk * 32;
    for (int idx = tid * 4; idx < 4096; idx += 2048) {
      int rr = idx >> 7, c = idx & 127;
      *(float4*)&ybuf[rr * 132 + c] = *(const float4*)&ybase[(size_t)(n0 + rr) * 128 + c];
    }
    __syncthreads();
    float acc[8];
#pragma unroll
    for (int u = 0; u < 8; ++u) acc[u] = 0.f;
    const float* yrow = &ybuf[r * 132];
    for (int i = 0; i < 128; ++i) {
      float yv = yrow[i];
      uint4 w = *(const uint4*)&ths[i * 128 + oc];
      float w0 = __uint_as_float(w.x << 16);
      float w1 = __uint_as_float(w.x & 0xffff0000u);
      float w2 = __uint_as_float(w.y << 16);
      float w3 = __uint_as_float(w.y & 0xffff0000u);
      float w4 = __uint_as_float(w.z << 16);
      float w5 = __uint_as_float(w.z & 0xffff0000u);
      float w6 = __uint_as_float(w.w << 16);
      float w7 = __uint_as_float(w.w & 0xffff0000u);
      acc[0] += yv * w0; acc[1] += yv * w1; acc[2] += yv * w2; acc[3] += yv * w3;
      acc[4] += yv * w4; acc[5] += yv * w5; acc[6] += yv * w6; acc[7] += yv * w7;
    }
    float sps = 0.f, spq = 0.f;
#pragma unroll
    for (int u = 0; u < 8; ++u) {
      acc[u] = fmaxf(acc[u], 0.f);
      sps += acc[u]; spq += acc[u] * acc[u];
    }
#pragma unroll
    for (int m = 8; m > 0; m >>= 1) {
      sps += __shfl_xor(sps, m, 16);
      spq += __shfl_xor(spq, m, 16);
    }
    float mm = sps * (1.f / 128.f);
    float rs = rsqrtf(spq * (1.f / 128.f) - mm * mm + 1e-5f);
    int n = n0 + r;
    size_t ga = ((size_t)(b * 256 + n)) * TILE + (size_t)t * 128 + oc;
    float4 xa = *(const float4*)&g0[ga];
    float4 xb4 = *(const float4*)&g0[ga + 4];
    float4 h0, h1;
    h0.x = (acc[0] - mm) * rs * gg[0] + bb[0] + xa.x + ev[0];
    h0.y = (acc[1] - mm) * rs * gg[1] + bb[1] + xa.y + ev[1];
    h0.z = (acc[2] - mm) * rs * gg[2] + bb[2] + xa.z + ev[2];
    h0.w = (acc[3] - mm) * rs * gg[3] + bb[3] + xa.w + ev[3];
    h1.x = (acc[4] - mm) * rs * gg[4] + bb[4] + xb4.x + ev[4];
    h1.y = (acc[5] - mm) * rs * gg[5] + bb[5] + xb4.y + ev[5];
    h1.z = (acc[6] - mm) * rs * gg[6] + bb[6] + xb4.z + ev[6];
    h1.w = (acc[7] - mm) * rs * gg[7] + bb[7] + xb4.w + ev[7];
    *(float4*)&g0[ga] = h0;
    *(float4*)&g0[ga + 4] = h1;
    __syncthreads();
  }
}

// ================================================================ megadec v3 — MFMA (r8-proven):
__global__ __launch_bounds__(512, 1) void k_megadec(
    const float* g0, const unsigned short* decW, const float* decb,
    const unsigned short* dxcW, const float* dxcb,
    const unsigned short* dc1W, const float* dc1b,
    const float* dp2w, const float* dp2b, const int* flag, void* outv) {
  int bn = blockIdx.x, b = bn >> 8, n = bn & 255;
  int f32o = flag[0];
  __shared__ unsigned short Bm[64 * SB];
  __shared__ unsigned short B2[64 * SB];
  __shared__ float pb0[8][64], pb1[8][64];
  int tid = threadIdx.x;
  int wv = tid >> 6, lane = tid & 63, quad = lane >> 4, lr = lane & 15;
  int m0 = wv * 16;
  const float* gp = g0 + (size_t)bn * TILE;
  for (int idx = tid * 4; idx < TILE; idx += 2048) {
    int t = idx >> 7, c = idx & 127;
    float4 v4 = *(const float4*)&gp[idx];
    ushort4 pk;
    pk.x = f2b(v4.x); pk.y = f2b(v4.y); pk.z = f2b(v4.z); pk.w = f2b(v4.w);
    *(ushort4*)&Bm[t * SB + 128 + c] = pk;
    if (t < 63) *(ushort4*)&Bm[(t + 1) * SB + c] = pk;
    if (t > 0)  *(ushort4*)&Bm[(t - 1) * SB + 256 + c] = pk;
  }
  if (tid < 128) {
    Bm[0 * SB + tid] = 0;  Bm[63 * SB + 256 + tid] = 0;
    B2[0 * SB + tid] = 0;  B2[63 * SB + 256 + tid] = 0;
  }
  __syncthreads();
  v4f acc[4];
  float ecv[4][4];
#pragma unroll
  for (int nt = 0; nt < 4; ++nt) acc[nt] = (v4f){0.f, 0.f, 0.f, 0.f};
  for (int kt = 0; kt < 12; ++kt) {
    v8s a = *(const v8s*)&decW[(m0 + lr) * 384 + kt * 32 + quad * 8];
#pragma unroll
    for (int nt = 0; nt < 4; ++nt) {
      v8s bb = *(const v8s*)&Bm[(nt * 16 + lr) * SB + kt * 32 + quad * 8];
      acc[nt] = __builtin_amdgcn_mfma_f32_16x16x32_bf16(a, bb, acc[nt], 0, 0, 0);
    }
  }
#pragma unroll
  for (int nt = 0; nt < 4; ++nt) {
    int t = nt * 16 + lr;
#pragma unroll
    for (int r = 0; r < 4; ++r) {
      int o = m0 + quad * 4 + r;
      float v = acc[nt][r] + decb[o];
      ecv[nt][r] = v;
      unsigned short bv = f2b(v);
      B2[t * SB + 128 + o] = bv;
      if (t < 63) B2[(t + 1) * SB + o] = bv;
      if (t > 0)  B2[(t - 1) * SB + 256 + o] = bv;
    }
  }
  __syncthreads();
  v4f ax[4], ac[4];
#pragma unroll
  for (int nt = 0; nt < 4; ++nt) { ax[nt] = (v4f){0.f,0.f,0.f,0.f}; ac[nt] = (v4f){0.f,0.f,0.f,0.f}; }
  for (int kt = 0; kt < 12; ++kt) {
    v8s a1 = *(const v8s*)&dxcW[(m0 + lr) * 384 + kt * 32 + quad * 8];
    v8s a2 = *(const v8s*)&dc1W[(m0 + lr) * 384 + kt * 32 + quad * 8];
#pragma unroll
    for (int nt = 0; nt < 4; ++nt) {
      v8s b1 = *(const v8s*)&Bm[(nt * 16 + lr) * SB + kt * 32 + quad * 8];
      v8s b2v = *(const v8s*)&B2[(nt * 16 + lr) * SB + kt * 32 + quad * 8];
      ax[nt] = __builtin_amdgcn_mfma_f32_16x16x32_bf16(a1, b1, ax[nt], 0, 0, 0);
      ac[nt] = __builtin_amdgcn_mfma_f32_16x16x32_bf16(a2, b2v, ac[nt], 0, 0, 0);
    }
  }
#pragma unroll
  for (int nt = 0; nt < 4; ++nt) {
    float p0 = 0.f, p1 = 0.f;
#pragma unroll
    for (int r = 0; r < 4; ++r) {
      int o = m0 + quad * 4 + r;
      float v = fmaxf(ax[nt][r] + dxcb[o] + sigm(ecv[nt][r]) + ac[nt][r] + dc1b[o], 0.f);
      p0 += v * dp2w[o];
      p1 += v * dp2w[128 + o];
    }
    p0 += __shfl_xor(p0, 16, 64); p0 += __shfl_xor(p0, 32, 64);
    p1 += __shfl_xor(p1, 16, 64); p1 += __shfl_xor(p1, 32, 64);
    if (quad == 0) { pb0[wv][nt * 16 + lr] = p0; pb1[wv][nt * 16 + lr] = p1; }
  }
  __syncthreads();
  if (tid < 128) {
    int ch = tid >> 6, t = tid & 63;
    float s = 0.f;
    if (ch == 0) { for (int w = 0; w < 8; ++w) s += pb0[w][t]; s += dp2b[0]; }
    else         { for (int w = 0; w < 8; ++w) s += pb1[w][t]; s += dp2b[1]; }
    size_t oi = ((size_t)(b * 2 + ch) * 256 + n) * 64 + t;
    if (f32o) ((float*)outv)[oi] = s;
    else ((__hip_bfloat16*)outv)[oi] = __float2bfloat16(s);
  }
}

}  // namespace

extern "C" void kernel_launch(void* const* d_in, const int* in_sizes, int n_in,
                              void* d_out, int out_size, void* d_ws, size_t ws_size,
                              hipStream_t stream) {
  (void)in_sizes; (void)n_in; (void)out_size; (void)ws_size;
  const void* x    = d_in[0];
  const void* adj  = d_in[1];
  const int*  step = (const int*)d_in[2];
  const void* wq   = d_in[3];
  const void* bq   = d_in[4];
  const void* wk   = d_in[5];
  const void* bk   = d_in[6];
  const void* w1   = d_in[7];
  const void* b1   = d_in[8];
  const void* w2   = d_in[9];
  const void* b2   = d_in[10];
  const void* th   = d_in[11];
  const void* l0g  = d_in[12];
  const void* l0b  = d_in[13];
  const void* l1g  = d_in[14];
  const void* l1b  = d_in[15];
  const void* p1w  = d_in[16];
  const void* p1b  = d_in[17];
  const void* p2w  = d_in[18];
  const void* p2b  = d_in[19];
  const void* dxcw = d_in[20];
  const void* dxcb = d_in[21];
  const void* decw = d_in[22];
  const void* decb = d_in[23];
  const void* dc1w = d_in[24];
  const void* dc1b = d_in[25];
  const void* dp2w = d_in[26];
  const void* dp2b = d_in[27];

  float* ws = (float*)d_ws;
  int* flag = (int*)ws;
  float* p = ws + 16;
  float* e     = p; p += 1024;
  float* lap   = p; p += 65536;
  float* wqkBv = p; p += 49152;   // 98304 bf16
  float* w1Bv  = p; p += 8192;    // 16384 bf16
  float* w2Bv  = p; p += 8192;
  float* thBv  = p; p += 8192;
  float* decWv = p; p += 24576;   // 49152 bf16
  float* dxcWv = p; p += 24576;
  float* dc1Wv = p; p += 24576;
  float* bqk   = p; p += 256;
  float* b1f   = p; p += 128;
  float* b2f   = p; p += 128;
  float* l0gf  = p; p += 128;
  float* l0bf  = p; p += 128;
  float* l1gf  = p; p += 128;
  float* l1bf  = p; p += 128;
  float* dxcbf = p; p += 128;
  float* decbf = p; p += 128;
  float* dc1bf = p; p += 128;
  float* dp2wf = p; p += 256;
  float* dp2bf = p; p += 8;
  size_t off = (size_t)(p - ws);
  off = (off + 127) & ~(size_t)127;
  float* xf = ws + off;            // BIGE floats scratch: y lives here after megasp
  float* g0 = xf + BIGE;           // BIGE floats (67 MB)

  PrepArgs pa;
  pa.flag = flag;
  pa.wq = wq; pa.wk = wk; pa.w1 = w1; pa.w2 = w2; pa.th = th;
  pa.dxc = dxcw; pa.dec = decw; pa.dc1 = dc1w;
  pa.bq = bq; pa.bk = bk; pa.b1 = b1; pa.b2 = b2;
  pa.l0g = l0g; pa.l0b = l0b; pa.l1g = l1g; pa.l1b = l1b;
  pa.dxcb = dxcb; pa.decb = decb; pa.dc1b = dc1b; pa.dp2w = dp2w; pa.dp2b = dp2b;
  pa.wqkB = (unsigned short*)wqkBv;
  pa.w1B = (unsigned short*)w1Bv;
  pa.w2B = (unsigned short*)w2Bv;
  pa.thB = (__hip_bfloat16*)thBv;
  pa.decWb = (unsigned short*)decWv;
  pa.dxcWb = (unsigned short*)dxcWv;
  pa.dc1Wb = (unsigned short*)dc1Wv;
  pa.bqk = bqk; pa.b1f = b1f; pa.b2f = b2f;
  pa.l0gf = l0gf; pa.l0bf = l0bf; pa.l1gf = l1gf; pa.l1bf = l1bf;
  pa.dxcbf = dxcbf; pa.decbf = decbf; pa.dc1bf = dc1bf; pa.dp2wf = dp2wf; pa.dp2bf = dp2bf;

  k_sniff<<<1, 64, 0, stream>>>((const unsigned short*)x, flag);
  k_prep<<<128, 256, 0, stream>>>(pa);
  k_lap<<<1, 256, 0, stream>>>(adj, flag, lap);
  k_emb<<<8, 128, 0, stream>>>(step, flag, p1w, p1b, p2w, p2b, e);

  k_mega1<<<2048, 512, 0, stream>>>(x, flag, (const unsigned short*)wqkBv, bqk,
                                    (const unsigned short*)w1Bv, b1f,
                                    (const unsigned short*)w2Bv, b2f, l0gf, l0bf, g0);
  k_megasp<<<512, 512, 0, stream>>>(g0, lap, xf);               // y -> xf
  k_theta<<<512, 512, 0, stream>>>(xf, (const unsigned short*)thBv, g0, l1gf, l1bf, e);
  k_megadec<<<2048, 512, 0, stream>>>(g0, (const unsigned short*)decWv, decbf,
                                      (const unsigned short*)dxcWv, dxcbf,
                                      (const unsigned short*)dc1Wv, dc1bf,
                                      dp2wf, dp2bf, flag, d_out);
}